// Round 3
// baseline (818.794 us; speedup 1.0000x reference)
//
#include <hip/hip_runtime.h>
#include <hip/hip_bf16.h>

#define N_NODES 50000
#define N_EDGES 300000
#define E_TOT   350000   /* edges + self loops */
#define N_GRAPHS 256
#define F_IN 78
#define H1 10
#define D1 780           /* H1*F_H1 */
#define F_OUT 128
#define NEG_SLOPE 0.2f
#define NB 196           /* ceil(50000/256) */

__device__ __forceinline__ int src_of(int e, const int* __restrict__ ei) {
  return (e < N_EDGES) ? ei[e] : (e - N_EDGES);
}
__device__ __forceinline__ int dst_of(int e, const int* __restrict__ ei) {
  return (e < N_EDGES) ? ei[N_EDGES + e] : (e - N_EDGES);
}
__device__ __forceinline__ float bf2f(unsigned short u) {
  return __uint_as_float(((unsigned int)u) << 16);
}
__device__ __forceinline__ float wave_max(float v) {
  #pragma unroll
  for (int msk = 32; msk > 0; msk >>= 1) v = fmaxf(v, __shfl_xor(v, msk));
  return v;
}
__device__ __forceinline__ float wave_sum(float v) {
  #pragma unroll
  for (int msk = 32; msk > 0; msk >>= 1) v += __shfl_xor(v, msk);
  return v;
}

/* ---------------- CSR build: degree, scan, scatter ---------------- */

__global__ void k_deg(const int* __restrict__ ei, int* __restrict__ deg) {
  int e = blockIdx.x * 256 + threadIdx.x;
  if (e >= E_TOT) return;
  atomicAdd(&deg[dst_of(e, ei)], 1);
}

__global__ void k_scan1(const int* __restrict__ deg, int* __restrict__ part) {
  __shared__ int s[256];
  int t = threadIdx.x;
  int i = blockIdx.x * 256 + t;
  s[t] = (i < N_NODES) ? deg[i] : 0;
  __syncthreads();
  for (int d = 128; d > 0; d >>= 1) {
    if (t < d) s[t] += s[t + d];
    __syncthreads();
  }
  if (t == 0) part[blockIdx.x] = s[0];
}

__global__ void k_scan2(const int* __restrict__ part, int* __restrict__ ppref) {
  if (threadIdx.x == 0) {
    int run = 0;
    for (int i = 0; i < NB; ++i) { ppref[i] = run; run += part[i]; }
  }
}

__global__ void k_scan3(const int* __restrict__ deg, const int* __restrict__ ppref,
                        int* __restrict__ offs, int* __restrict__ cursor) {
  __shared__ int s[256];
  int t = threadIdx.x;
  int i = blockIdx.x * 256 + t;
  int v = (i < N_NODES) ? deg[i] : 0;
  s[t] = v;
  __syncthreads();
  for (int d = 1; d < 256; d <<= 1) {
    int u = (t >= d) ? s[t - d] : 0;
    __syncthreads();
    s[t] += u;
    __syncthreads();
  }
  int excl = s[t] - v;
  if (i < N_NODES) {
    int off = ppref[blockIdx.x] + excl;
    offs[i] = off;
    cursor[i] = off;
  }
}

__global__ void k_scatter(const int* __restrict__ ei, int* __restrict__ cursor,
                          int* __restrict__ src_s) {
  int e = blockIdx.x * 256 + threadIdx.x;
  if (e >= E_TOT) return;
  int s = src_of(e, ei);
  int d = dst_of(e, ei);
  int pos = atomicAdd(&cursor[d], 1);
  src_s[pos] = s;
}

/* ---- was[k,h] = sum_f W1[k, h*78+f] * a_src1[h*78+f]; same for wad ---- */

__global__ void k_prep(const float* __restrict__ W1, const float* __restrict__ as1,
                       const float* __restrict__ ad1, float* __restrict__ was,
                       float* __restrict__ wad) {
  int i = blockIdx.x * 256 + threadIdx.x;
  if (i >= F_IN * H1) return;
  int k = i / H1, h = i - k * H1;
  const float* wrow = W1 + (size_t)k * D1 + h * 78;
  const float* ar = as1 + h * 78;
  const float* br = ad1 + h * 78;
  float s = 0.f, d = 0.f;
  for (int f = 0; f < 78; ++f) {
    float w = wrow[f];
    s = fmaf(w, ar[f], s);
    d = fmaf(w, br[f], d);
  }
  was[i] = s;  /* layout [k][h], stride H1 */
  wad[i] = d;
}

/* ---- als1[n,h] = x[n,:] . was[:,h] ; ald1 likewise (LDS-staged) ---- */

__global__ __launch_bounds__(320) void k_logits1(const float* __restrict__ x,
                                                 const float* __restrict__ was,
                                                 const float* __restrict__ wad,
                                                 float* __restrict__ als,
                                                 float* __restrict__ ald) {
  __shared__ float xs[32][81];
  __shared__ float wl[D1], wl2[D1];
  int tid = threadIdx.x;
  int n0 = blockIdx.x * 32;
  for (int i = tid; i < 32 * F_IN; i += 320) {
    int r = i / F_IN, k = i - r * F_IN;
    int n = n0 + r;
    xs[r][k] = (n < N_NODES) ? x[(size_t)n * F_IN + k] : 0.f;
  }
  for (int i = tid; i < D1; i += 320) { wl[i] = was[i]; wl2[i] = wad[i]; }
  __syncthreads();
  int r = tid / 10, h = tid - r * 10;
  int n = n0 + r;
  float s = 0.f, d = 0.f;
  for (int k = 0; k < F_IN; ++k) {
    float xv = xs[r][k];
    s = fmaf(xv, wl[k * 10 + h], s);
    d = fmaf(xv, wl2[k * 10 + h], d);
  }
  if (n < N_NODES) { als[n * 10 + h] = s; ald[n * 10 + h] = d; }
}

/* ---- fused layer 1: in-wave softmax + alpha-weighted x gather + per-head
   matmul with W1 + bias + ELU -> bf16 out1.  10 nodes/block, 5 waves. ---- */

__global__ __launch_bounds__(320, 4) void k_agg1f(const float* __restrict__ x,
                                                  const float* __restrict__ als1,
                                                  const float* __restrict__ ald1,
                                                  const int* __restrict__ src_s,
                                                  const int* __restrict__ offs,
                                                  const int* __restrict__ deg,
                                                  const float* __restrict__ W1,
                                                  const float* __restrict__ b1,
                                                  __hip_bfloat16* __restrict__ out1) {
  __shared__ float xagg[10][H1][80];
  int tid = threadIdx.x, wv = tid >> 6, lane = tid & 63;
  int n0 = blockIdx.x * 10;

  /* phase 1: per wave, two nodes; online softmax in registers via butterflies */
  #pragma unroll
  for (int rep = 0; rep < 2; ++rep) {
    int g = wv * 2 + rep;
    int n = n0 + g;
    int o = offs[n], d = deg[n];
    float aldn[H1];
    #pragma unroll
    for (int h = 0; h < H1; ++h) aldn[h] = ald1[n * H1 + h];
    float m[H1], s[H1], acc[H1], acc2[H1];
    #pragma unroll
    for (int h = 0; h < H1; ++h) { m[h] = -1e30f; s[h] = 0.f; acc[h] = 0.f; acc2[h] = 0.f; }

    for (int base = 0; base < d; base += 64) {
      int cnt = min(64, d - base);
      int sb_l = 0;
      float w[H1];
      if (lane < cnt) {
        sb_l = src_s[o + base + lane];
        const float* alr = als1 + (size_t)sb_l * H1;
        #pragma unroll
        for (int h = 0; h < H1; ++h) {
          float v = alr[h] + aldn[h];
          w[h] = (v > 0.f) ? v : NEG_SLOPE * v;
        }
      } else {
        #pragma unroll
        for (int h = 0; h < H1; ++h) w[h] = -1e30f;
      }
      #pragma unroll
      for (int h = 0; h < H1; ++h) {
        float mC = wave_max(w[h]);
        float mN = fmaxf(m[h], mC);
        float scale = __expf(m[h] - mN);   /* first chunk: exp(-inf)=0, acc=0 */
        float wv_ = __expf(w[h] - mN);     /* inactive lanes -> 0 */
        float sC = wave_sum(wv_);
        s[h] = s[h] * scale + sC;
        acc[h] *= scale;
        acc2[h] *= scale;
        m[h] = mN;
        w[h] = wv_;
      }
      for (int j = 0; j < cnt; ++j) {
        int sb = __shfl(sb_l, j);
        const float* xr = x + (size_t)sb * F_IN;
        float xv = xr[lane];
        float xv2 = (lane < F_IN - 64) ? xr[64 + lane] : 0.f;
        #pragma unroll
        for (int h = 0; h < H1; ++h) {
          float a = __shfl(w[h], j);
          acc[h] = fmaf(a, xv, acc[h]);
          acc2[h] = fmaf(a, xv2, acc2[h]);
        }
      }
    }
    #pragma unroll
    for (int h = 0; h < H1; ++h) {
      float inv = 1.f / s[h];
      xagg[g][h][lane] = acc[h] * inv;
      if (lane < 16) xagg[g][h][64 + lane] = (lane < F_IN - 64) ? acc2[h] * inv : 0.f;
    }
  }
  __syncthreads();

  /* phase 2: out1[g, h*78 + j0 + {0,26,52}] = xagg[g,h,:] . W1 cols, +b1, ELU */
  if (tid < 260) {
    int h = tid / 26, j0 = tid - h * 26;
    int c0 = h * 78 + j0;
    float s2[10][3];
    #pragma unroll
    for (int g = 0; g < 10; ++g)
      #pragma unroll
      for (int q = 0; q < 3; ++q) s2[g][q] = 0.f;

    for (int k = 0; k < 76; k += 4) {
      float wq[3][4];
      #pragma unroll
      for (int q = 0; q < 3; ++q)
        #pragma unroll
        for (int kk = 0; kk < 4; ++kk)
          wq[q][kk] = W1[(size_t)(k + kk) * D1 + c0 + q * 26];
      #pragma unroll
      for (int g = 0; g < 10; ++g) {
        float4 xa = *reinterpret_cast<const float4*>(&xagg[g][h][k]);
        #pragma unroll
        for (int q = 0; q < 3; ++q) {
          s2[g][q] = fmaf(xa.x, wq[q][0], s2[g][q]);
          s2[g][q] = fmaf(xa.y, wq[q][1], s2[g][q]);
          s2[g][q] = fmaf(xa.z, wq[q][2], s2[g][q]);
          s2[g][q] = fmaf(xa.w, wq[q][3], s2[g][q]);
        }
      }
    }
    #pragma unroll
    for (int kk = 0; kk < 2; ++kk) {   /* tail k = 76,77 */
      int k = 76 + kk;
      float w0 = W1[(size_t)k * D1 + c0];
      float w1 = W1[(size_t)k * D1 + c0 + 26];
      float w2 = W1[(size_t)k * D1 + c0 + 52];
      #pragma unroll
      for (int g = 0; g < 10; ++g) {
        float xv = xagg[g][h][k];
        s2[g][0] = fmaf(xv, w0, s2[g][0]);
        s2[g][1] = fmaf(xv, w1, s2[g][1]);
        s2[g][2] = fmaf(xv, w2, s2[g][2]);
      }
    }
    #pragma unroll
    for (int q = 0; q < 3; ++q) {
      int c = c0 + q * 26;
      float bv = b1[c];
      #pragma unroll
      for (int g = 0; g < 10; ++g) {
        float v = s2[g][q] + bv;
        v = (v > 0.f) ? v : expm1f(v);  /* ELU */
        out1[(size_t)(n0 + g) * D1 + c] = __float2bfloat16(v);
      }
    }
  }
}

/* ---------------- GEMM2: h2[50000,128] = out1(bf16)[50000,780] @ W2 ---------------- */

__global__ __launch_bounds__(256) void k_gemm2(const __hip_bfloat16* __restrict__ A,
                                               const float* __restrict__ W2,
                                               float* __restrict__ C) {
  __shared__ __align__(16) float sA[64][68];
  __shared__ __align__(16) float sB[64][128];
  int m0 = blockIdx.x * 64;
  int tid = threadIdx.x;
  int cg = tid & 15, rg = tid >> 4;
  float acc[4][8];
  #pragma unroll
  for (int r = 0; r < 4; ++r)
    #pragma unroll
    for (int j = 0; j < 8; ++j) acc[r][j] = 0.f;

  for (int k0 = 0; k0 < D1; k0 += 64) {
    for (int t = tid; t < 1024; t += 256) {
      int mm = t >> 4, kq = t & 15;
      int gm = m0 + mm, gk = k0 + kq * 4;
      float4 v = make_float4(0.f, 0.f, 0.f, 0.f);
      if (gm < N_NODES && gk < D1) {
        ushort4 u = *reinterpret_cast<const ushort4*>(&A[(size_t)gm * D1 + gk]);
        v.x = bf2f(u.x); v.y = bf2f(u.y); v.z = bf2f(u.z); v.w = bf2f(u.w);
      }
      *reinterpret_cast<float4*>(&sA[mm][kq * 4]) = v;
    }
    for (int t = tid; t < 2048; t += 256) {
      int k = t >> 5, cq = t & 31;
      int gk = k0 + k;
      float4 v = make_float4(0.f, 0.f, 0.f, 0.f);
      if (gk < D1)
        v = *reinterpret_cast<const float4*>(&W2[(size_t)gk * F_OUT + cq * 4]);
      *reinterpret_cast<float4*>(&sB[k][cq * 4]) = v;
    }
    __syncthreads();
    #pragma unroll 4
    for (int k = 0; k < 64; ++k) {
      float a0 = sA[rg * 4 + 0][k];
      float a1 = sA[rg * 4 + 1][k];
      float a2 = sA[rg * 4 + 2][k];
      float a3 = sA[rg * 4 + 3][k];
      float4 b0 = *reinterpret_cast<const float4*>(&sB[k][cg * 8]);
      float4 b1v = *reinterpret_cast<const float4*>(&sB[k][cg * 8 + 4]);
      float bb[8] = {b0.x, b0.y, b0.z, b0.w, b1v.x, b1v.y, b1v.z, b1v.w};
      #pragma unroll
      for (int j = 0; j < 8; ++j) {
        acc[0][j] = fmaf(a0, bb[j], acc[0][j]);
        acc[1][j] = fmaf(a1, bb[j], acc[1][j]);
        acc[2][j] = fmaf(a2, bb[j], acc[2][j]);
        acc[3][j] = fmaf(a3, bb[j], acc[3][j]);
      }
    }
    __syncthreads();
  }
  #pragma unroll
  for (int r = 0; r < 4; ++r) {
    int gm = m0 + rg * 4 + r;
    if (gm < N_NODES) {
      float4 v0 = make_float4(acc[r][0], acc[r][1], acc[r][2], acc[r][3]);
      float4 v1 = make_float4(acc[r][4], acc[r][5], acc[r][6], acc[r][7]);
      *reinterpret_cast<float4*>(&C[(size_t)gm * F_OUT + cg * 8]) = v0;
      *reinterpret_cast<float4*>(&C[(size_t)gm * F_OUT + cg * 8 + 4]) = v1;
    }
  }
}

/* ---------------- layer 2 attention logits ---------------- */

__global__ __launch_bounds__(64) void k_al2(const float* __restrict__ h2,
                                            const float* __restrict__ asrc,
                                            const float* __restrict__ adst,
                                            float* __restrict__ als,
                                            float* __restrict__ ald) {
  int n = blockIdx.x, lane = threadIdx.x;
  const float* hp = h2 + (size_t)n * F_OUT;
  float h0 = hp[lane], h64 = hp[64 + lane];
  float s = h0 * asrc[lane] + h64 * asrc[64 + lane];
  float d = h0 * adst[lane] + h64 * adst[64 + lane];
  #pragma unroll
  for (int off = 32; off > 0; off >>= 1) {
    s += __shfl_down(s, off);
    d += __shfl_down(d, off);
  }
  if (lane == 0) { als[n] = s; ald[n] = d; }
}

/* ---- fused layer 2: in-wave softmax + gather-aggregate + bias + ReLU ---- */

__global__ __launch_bounds__(128) void k_agg2f(const float* __restrict__ h2,
                                               const float* __restrict__ als2,
                                               const float* __restrict__ ald2,
                                               const int* __restrict__ src_s,
                                               const int* __restrict__ offs,
                                               const int* __restrict__ deg,
                                               const float* __restrict__ b2,
                                               float* __restrict__ out2) {
  int n = blockIdx.x;
  int tid = threadIdx.x, lane = tid & 63;
  int o = offs[n], d = deg[n];
  float aldn = ald2[n];
  float m = -1e30f, s = 0.f, acc = 0.f;
  for (int base = 0; base < d; base += 64) {
    int cnt = min(64, d - base);
    int sb_l = 0;
    float raw = -1e30f;
    if (lane < cnt) {
      sb_l = src_s[o + base + lane];
      float v = als2[sb_l] + aldn;
      raw = (v > 0.f) ? v : NEG_SLOPE * v;
    }
    float mC = wave_max(raw);
    float mN = fmaxf(m, mC);
    float scale = __expf(m - mN);
    float w = __expf(raw - mN);
    s = s * scale + wave_sum(w);
    acc *= scale;
    m = mN;
    for (int j = 0; j < cnt; ++j) {
      float a = __shfl(w, j);
      int sb = __shfl(sb_l, j);
      acc = fmaf(a, h2[(size_t)sb * F_OUT + tid], acc);
    }
  }
  float v = acc / s + b2[tid];
  out2[(size_t)n * F_OUT + tid] = fmaxf(v, 0.f);
}

/* ---------------- pool (batch is sorted) + fc ---------------- */

__global__ __launch_bounds__(128) void k_pool(const float* __restrict__ out2,
                                              const int* __restrict__ batch,
                                              unsigned int* __restrict__ g) {
  int b = blockIdx.x;
  int start = b * 256, end = min(start + 256, N_NODES);
  int f = threadIdx.x;
  int n = start;
  while (n < end) {
    int gc = batch[n];
    float mx = 0.f;
    do {
      mx = fmaxf(mx, out2[(size_t)n * F_OUT + f]);
      ++n;
    } while (n < end && batch[n] == gc);
    atomicMax(&g[gc * F_OUT + f], __float_as_uint(mx));
  }
}

__global__ __launch_bounds__(128) void k_fc(const float* __restrict__ g,
                                            const float* __restrict__ fc_w,
                                            const float* __restrict__ fc_b,
                                            float* __restrict__ out) {
  int b = blockIdx.x, c = threadIdx.x;
  const float* gr = g + (size_t)b * F_OUT;
  float acc = 0.f;
  for (int k = 0; k < F_OUT; ++k) acc = fmaf(gr[k], fc_w[k * F_OUT + c], acc);
  float v = acc + fc_b[c];
  out[(size_t)b * F_OUT + c] = fmaxf(v, 0.f);
}

/* ---------------- launch ---------------- */

extern "C" void kernel_launch(void* const* d_in, const int* in_sizes, int n_in,
                              void* d_out, int out_size, void* d_ws, size_t ws_size,
                              hipStream_t stream) {
  const float* x      = (const float*)d_in[0];
  const int*   ei     = (const int*)  d_in[1];
  const int*   batch  = (const int*)  d_in[2];
  const float* W1     = (const float*)d_in[3];
  const float* a_src1 = (const float*)d_in[4];
  const float* a_dst1 = (const float*)d_in[5];
  const float* b1     = (const float*)d_in[6];
  const float* W2     = (const float*)d_in[7];
  const float* a_src2 = (const float*)d_in[8];
  const float* a_dst2 = (const float*)d_in[9];
  const float* b2     = (const float*)d_in[10];
  const float* fc_w   = (const float*)d_in[11];
  const float* fc_b   = (const float*)d_in[12];
  float* out = (float*)d_out;

  float* ws = (float*)d_ws;
  /* footprint ~= 34.4M floats = 138 MB */
  __hip_bfloat16* out1 = (__hip_bfloat16*)ws;   /* 39,000,000 bf16 = 19.5M floats */
  float* h2   = ws + 19500000;            /* 6,400,000 */
  float* out2 = ws + 25900000;            /* 6,400,000 */
  float* als1 = ws + 32300000;            /*   500,000 */
  float* ald1 = ws + 32800000;            /*   500,000 */
  float* als2 = ws + 33300000;            /*    50,000 */
  float* ald2 = ws + 33350000;            /*    50,000 */
  float* g    = ws + 33400000;            /*    32,768 */
  float* was  = ws + 33440000;            /*       780 */
  float* wad  = ws + 33441000;            /*       780 */
  int* ib     = (int*)(ws + 33442000);
  int* deg    = ib;                        /*  50,000 */
  int* offs   = ib + 50000;
  int* cursor = ib + 100000;
  int* src_s  = ib + 150000;               /* 350,000 */
  int* part   = ib + 500000;               /* 196 */
  int* ppref  = ib + 500224;               /* 196 */

  /* CSR build */
  hipMemsetAsync(deg, 0, N_NODES * sizeof(int), stream);
  k_deg<<<(E_TOT + 255) / 256, 256, 0, stream>>>(ei, deg);
  k_scan1<<<NB, 256, 0, stream>>>(deg, part);
  k_scan2<<<1, 64, 0, stream>>>(part, ppref);
  k_scan3<<<NB, 256, 0, stream>>>(deg, ppref, offs, cursor);
  k_scatter<<<(E_TOT + 255) / 256, 256, 0, stream>>>(ei, cursor, src_s);

  /* layer 1 */
  k_prep<<<4, 256, 0, stream>>>(W1, a_src1, a_dst1, was, wad);
  k_logits1<<<(N_NODES + 31) / 32, 320, 0, stream>>>(x, was, wad, als1, ald1);
  k_agg1f<<<N_NODES / 10, 320, 0, stream>>>(x, als1, ald1, src_s, offs, deg, W1, b1, out1);

  /* layer 2 */
  k_gemm2<<<(N_NODES + 63) / 64, 256, 0, stream>>>(out1, W2, h2);
  k_al2<<<N_NODES, 64, 0, stream>>>(h2, a_src2, a_dst2, als2, ald2);
  k_agg2f<<<N_NODES, 128, 0, stream>>>(h2, als2, ald2, src_s, offs, deg, b2, out2);

  /* pool + fc */
  hipMemsetAsync(g, 0, N_GRAPHS * F_OUT * sizeof(float), stream);
  k_pool<<<NB, 128, 0, stream>>>(out2, batch, (unsigned int*)g);
  k_fc<<<N_GRAPHS, F_OUT, 0, stream>>>(g, fc_w, fc_b, out);
}

// Round 4
// 670.630 us; speedup vs baseline: 1.2209x; 1.2209x over previous
//
#include <hip/hip_runtime.h>
#include <hip/hip_bf16.h>

#define N_NODES 50000
#define N_EDGES 300000
#define E_TOT   350000   /* edges + self loops */
#define N_GRAPHS 256
#define F_IN 78
#define H1 10
#define D1 780           /* H1*F_H1 */
#define F_OUT 128
#define KP 800           /* K padded for MFMA (780 -> 800) */
#define NEG_SLOPE 0.2f
#define NB 196           /* ceil(50000/256) */

typedef float v4f __attribute__((ext_vector_type(4)));
typedef short v8s __attribute__((ext_vector_type(8)));

__device__ __forceinline__ int src_of(int e, const int* __restrict__ ei) {
  return (e < N_EDGES) ? ei[e] : (e - N_EDGES);
}
__device__ __forceinline__ int dst_of(int e, const int* __restrict__ ei) {
  return (e < N_EDGES) ? ei[N_EDGES + e] : (e - N_EDGES);
}

/* ---------------- CSR build: degree, scan, scatter ---------------- */

__global__ void k_deg(const int* __restrict__ ei, int* __restrict__ deg) {
  int e = blockIdx.x * 256 + threadIdx.x;
  if (e >= E_TOT) return;
  atomicAdd(&deg[dst_of(e, ei)], 1);
}

__global__ void k_scan1(const int* __restrict__ deg, int* __restrict__ part) {
  __shared__ int s[256];
  int t = threadIdx.x;
  int i = blockIdx.x * 256 + t;
  s[t] = (i < N_NODES) ? deg[i] : 0;
  __syncthreads();
  for (int d = 128; d > 0; d >>= 1) {
    if (t < d) s[t] += s[t + d];
    __syncthreads();
  }
  if (t == 0) part[blockIdx.x] = s[0];
}

__global__ void k_scan2(const int* __restrict__ part, int* __restrict__ ppref) {
  if (threadIdx.x == 0) {
    int run = 0;
    for (int i = 0; i < NB; ++i) { ppref[i] = run; run += part[i]; }
  }
}

__global__ void k_scan3(const int* __restrict__ deg, const int* __restrict__ ppref,
                        int* __restrict__ offs, int* __restrict__ cursor) {
  __shared__ int s[256];
  int t = threadIdx.x;
  int i = blockIdx.x * 256 + t;
  int v = (i < N_NODES) ? deg[i] : 0;
  s[t] = v;
  __syncthreads();
  for (int d = 1; d < 256; d <<= 1) {
    int u = (t >= d) ? s[t - d] : 0;
    __syncthreads();
    s[t] += u;
    __syncthreads();
  }
  int excl = s[t] - v;
  if (i < N_NODES) {
    int off = ppref[blockIdx.x] + excl;
    offs[i] = off;
    cursor[i] = off;
  }
}

__global__ void k_scatter(const int* __restrict__ ei, int* __restrict__ cursor,
                          int* __restrict__ src_s) {
  int e = blockIdx.x * 256 + threadIdx.x;
  if (e >= E_TOT) return;
  int s = src_of(e, ei);
  int d = dst_of(e, ei);
  int pos = atomicAdd(&cursor[d], 1);
  src_s[pos] = s;
}

/* ---- was[k,h] = sum_f W1[k, h*78+f] * a_src1[h*78+f]; same for wad ---- */

__global__ void k_prep(const float* __restrict__ W1, const float* __restrict__ as1,
                       const float* __restrict__ ad1, float* __restrict__ was,
                       float* __restrict__ wad) {
  int i = blockIdx.x * 256 + threadIdx.x;
  if (i >= F_IN * H1) return;
  int k = i / H1, h = i - k * H1;
  const float* wrow = W1 + (size_t)k * D1 + h * 78;
  const float* ar = as1 + h * 78;
  const float* br = ad1 + h * 78;
  float s = 0.f, d = 0.f;
  for (int f = 0; f < 78; ++f) {
    float w = wrow[f];
    s = fmaf(w, ar[f], s);
    d = fmaf(w, br[f], d);
  }
  was[i] = s;  /* layout [k][h] */
  wad[i] = d;
}

/* ---- als1[n,h] = x[n,:] . was[:,h] ; ald1 likewise (LDS-staged) ---- */

__global__ __launch_bounds__(320) void k_logits1(const float* __restrict__ x,
                                                 const float* __restrict__ was,
                                                 const float* __restrict__ wad,
                                                 float* __restrict__ als,
                                                 float* __restrict__ ald) {
  __shared__ float xs[32][81];
  __shared__ float wl[D1], wl2[D1];
  int tid = threadIdx.x;
  int n0 = blockIdx.x * 32;
  for (int i = tid; i < 32 * F_IN; i += 320) {
    int r = i / F_IN, k = i - r * F_IN;
    int n = n0 + r;
    xs[r][k] = (n < N_NODES) ? x[(size_t)n * F_IN + k] : 0.f;
  }
  for (int i = tid; i < D1; i += 320) { wl[i] = was[i]; wl2[i] = wad[i]; }
  __syncthreads();
  int r = tid / 10, h = tid - r * 10;
  int n = n0 + r;
  float s = 0.f, d = 0.f;
  for (int k = 0; k < F_IN; ++k) {
    float xv = xs[r][k];
    s = fmaf(xv, wl[k * 10 + h], s);
    d = fmaf(xv, wl2[k * 10 + h], d);
  }
  if (n < N_NODES) { als[n * 10 + h] = s; ald[n * 10 + h] = d; }
}

/* ---- layer-1 softmax: thread per (node, head); writes normalized alpha
   in CSR order: alpha1[pos*10 + h] ---- */

__global__ void k_soft1(const float* __restrict__ als1, const float* __restrict__ ald1,
                        const int* __restrict__ src_s, const int* __restrict__ offs,
                        const int* __restrict__ deg, float* __restrict__ alpha1) {
  int i = blockIdx.x * 256 + threadIdx.x;
  if (i >= N_NODES * H1) return;
  int n = i / H1, h = i - n * H1;
  int o = offs[n], dg = deg[n];
  float aldn = ald1[i];
  float m = -1e30f;
  for (int j = 0; j < dg; ++j) {
    float v = als1[src_s[o + j] * H1 + h] + aldn;
    v = (v > 0.f) ? v : NEG_SLOPE * v;
    m = fmaxf(m, v);
  }
  float s = 0.f;
  for (int j = 0; j < dg; ++j) {
    float v = als1[src_s[o + j] * H1 + h] + aldn;
    v = (v > 0.f) ? v : NEG_SLOPE * v;
    s += __expf(v - m);
  }
  float inv = 1.f / s;
  for (int j = 0; j < dg; ++j) {
    float v = als1[src_s[o + j] * H1 + h] + aldn;
    v = (v > 0.f) ? v : NEG_SLOPE * v;
    alpha1[(size_t)(o + j) * H1 + h] = __expf(v - m) * inv;
  }
}

/* ---- fused layer 1: weighted x gather (pre-normalized alpha) + per-head
   matmul with W1 + bias + ELU -> bf16 out1.  10 nodes/block, 5 waves. ---- */

__global__ __launch_bounds__(320) void k_agg1f(const float* __restrict__ x,
                                               const float* __restrict__ alpha1,
                                               const int* __restrict__ src_s,
                                               const int* __restrict__ offs,
                                               const int* __restrict__ deg,
                                               const float* __restrict__ W1,
                                               const float* __restrict__ b1,
                                               __hip_bfloat16* __restrict__ out1) {
  __shared__ float xagg[10][H1][80];
  int tid = threadIdx.x, wv = tid >> 6, lane = tid & 63;
  int n0 = blockIdx.x * 10;

  /* phase 1: wave handles 2 nodes; pure alpha-weighted gather */
  #pragma unroll
  for (int rep = 0; rep < 2; ++rep) {
    int g = wv * 2 + rep;
    int n = n0 + g;
    int o = offs[n], d = deg[n];
    float acc[H1], acc2[H1];
    #pragma unroll
    for (int h = 0; h < H1; ++h) { acc[h] = 0.f; acc2[h] = 0.f; }
    for (int j = 0; j < d; ++j) {
      int e = o + j;
      int sb = src_s[e];                    /* uniform -> scalar load */
      const float* xr = x + (size_t)sb * F_IN;
      float xv = xr[lane];
      float xv2 = (lane < F_IN - 64) ? xr[64 + lane] : 0.f;
      const float* ar = alpha1 + (size_t)e * H1;  /* uniform -> SGPRs */
      #pragma unroll
      for (int h = 0; h < H1; ++h) {
        float a = ar[h];
        acc[h] = fmaf(a, xv, acc[h]);
        acc2[h] = fmaf(a, xv2, acc2[h]);
      }
    }
    #pragma unroll
    for (int h = 0; h < H1; ++h) {
      xagg[g][h][lane] = acc[h];
      if (lane < 16) xagg[g][h][64 + lane] = (lane < F_IN - 64) ? acc2[h] : 0.f;
    }
  }
  __syncthreads();

  /* phase 2: out1[g, h*78 + j0 + {0,26,52}] = xagg[g,h,:] . W1 cols, +b1, ELU */
  if (tid < 260) {
    int h = tid / 26, j0 = tid - h * 26;
    int c0 = h * 78 + j0;
    float s2[10][3];
    #pragma unroll
    for (int g = 0; g < 10; ++g)
      #pragma unroll
      for (int q = 0; q < 3; ++q) s2[g][q] = 0.f;

    for (int k = 0; k < 76; k += 4) {
      float wq[3][4];
      #pragma unroll
      for (int q = 0; q < 3; ++q)
        #pragma unroll
        for (int kk = 0; kk < 4; ++kk)
          wq[q][kk] = W1[(size_t)(k + kk) * D1 + c0 + q * 26];
      #pragma unroll
      for (int g = 0; g < 10; ++g) {
        float4 xa = *reinterpret_cast<const float4*>(&xagg[g][h][k]);
        #pragma unroll
        for (int q = 0; q < 3; ++q) {
          s2[g][q] = fmaf(xa.x, wq[q][0], s2[g][q]);
          s2[g][q] = fmaf(xa.y, wq[q][1], s2[g][q]);
          s2[g][q] = fmaf(xa.z, wq[q][2], s2[g][q]);
          s2[g][q] = fmaf(xa.w, wq[q][3], s2[g][q]);
        }
      }
    }
    #pragma unroll
    for (int kk = 0; kk < 2; ++kk) {   /* tail k = 76,77 */
      int k = 76 + kk;
      float w0 = W1[(size_t)k * D1 + c0];
      float w1 = W1[(size_t)k * D1 + c0 + 26];
      float w2 = W1[(size_t)k * D1 + c0 + 52];
      #pragma unroll
      for (int g = 0; g < 10; ++g) {
        float xv = xagg[g][h][k];
        s2[g][0] = fmaf(xv, w0, s2[g][0]);
        s2[g][1] = fmaf(xv, w1, s2[g][1]);
        s2[g][2] = fmaf(xv, w2, s2[g][2]);
      }
    }
    #pragma unroll
    for (int q = 0; q < 3; ++q) {
      int c = c0 + q * 26;
      float bv = b1[c];
      #pragma unroll
      for (int g = 0; g < 10; ++g) {
        float v = s2[g][q] + bv;
        v = (v > 0.f) ? v : expm1f(v);  /* ELU */
        out1[(size_t)(n0 + g) * D1 + c] = __float2bfloat16(v);
      }
    }
  }
}

/* ---- W2 [780][128] fp32 -> W2T [128][800] bf16 (zero-padded K) ---- */

__global__ void k_w2t(const float* __restrict__ W2, __hip_bfloat16* __restrict__ Bt) {
  int i = blockIdx.x * 256 + threadIdx.x;
  if (i >= F_OUT * KP) return;
  int c = i / KP, k = i - c * KP;
  float v = (k < D1) ? W2[(size_t)k * F_OUT + c] : 0.f;
  Bt[i] = __float2bfloat16(v);
}

/* ---- GEMM2 via MFMA: h2[50000,128] = out1(bf16) @ W2T^T.
   Block 256 = 4 waves (2x2), tile 64x128, K=800, no LDS:
   A frag: row=lane&15, k=(lane>>4)*8+j (8 contiguous bf16)
   B frag: col=lane&15, k=(lane>>4)*8+j (W2T k-contiguous)
   C/D:    col=lane&15, row=(lane>>4)*4+reg  [verified m89] ---- */

__global__ __launch_bounds__(256) void k_gemm2m(const __hip_bfloat16* __restrict__ A,
                                                const __hip_bfloat16* __restrict__ Bt,
                                                float* __restrict__ C) {
  int tid = threadIdx.x;
  int wid = tid >> 6, lane = tid & 63;
  int wr = wid >> 1, wc = wid & 1;
  int m0 = blockIdx.x * 64;
  int row16 = lane & 15, kchunk = (lane >> 4) * 8;
  v4f acc[2][4];
  #pragma unroll
  for (int ri = 0; ri < 2; ++ri)
    #pragma unroll
    for (int nf = 0; nf < 4; ++nf) acc[ri][nf] = (v4f){0.f, 0.f, 0.f, 0.f};

  const unsigned short* Ap = (const unsigned short*)A;
  const unsigned short* Bp = (const unsigned short*)Bt;

  for (int k0 = 0; k0 < KP; k0 += 32) {
    int ka = k0 + kchunk;
    v8s a[2], b[4];
    #pragma unroll
    for (int ri = 0; ri < 2; ++ri) {
      const unsigned short* p = Ap + (size_t)(m0 + wr * 32 + ri * 16 + row16) * D1 + ka;
      union { uint2 q[2]; v8s v; } u;
      u.q[0] = *reinterpret_cast<const uint2*>(p);
      u.q[1] = *reinterpret_cast<const uint2*>(p + 4);
      a[ri] = u.v;
    }
    #pragma unroll
    for (int nf = 0; nf < 4; ++nf) {
      const unsigned short* p = Bp + (size_t)(wc * 64 + nf * 16 + row16) * KP + ka;
      b[nf] = *reinterpret_cast<const v8s*>(p);
    }
    #pragma unroll
    for (int ri = 0; ri < 2; ++ri)
      #pragma unroll
      for (int nf = 0; nf < 4; ++nf)
        acc[ri][nf] = __builtin_amdgcn_mfma_f32_16x16x32_bf16(a[ri], b[nf], acc[ri][nf], 0, 0, 0);
  }
  #pragma unroll
  for (int ri = 0; ri < 2; ++ri) {
    int rbase = m0 + wr * 32 + ri * 16 + (lane >> 4) * 4;
    #pragma unroll
    for (int r = 0; r < 4; ++r) {
      int gm = rbase + r;
      if (gm < N_NODES) {
        #pragma unroll
        for (int nf = 0; nf < 4; ++nf)
          C[(size_t)gm * F_OUT + wc * 64 + nf * 16 + (lane & 15)] = acc[ri][nf][r];
      }
    }
  }
}

/* ---------------- layer 2 attention ---------------- */

__global__ __launch_bounds__(64) void k_al2(const float* __restrict__ h2,
                                            const float* __restrict__ asrc,
                                            const float* __restrict__ adst,
                                            float* __restrict__ als,
                                            float* __restrict__ ald) {
  int n = blockIdx.x, lane = threadIdx.x;
  const float* hp = h2 + (size_t)n * F_OUT;
  float h0 = hp[lane], h64 = hp[64 + lane];
  float s = h0 * asrc[lane] + h64 * asrc[64 + lane];
  float d = h0 * adst[lane] + h64 * adst[64 + lane];
  #pragma unroll
  for (int off = 32; off > 0; off >>= 1) {
    s += __shfl_down(s, off);
    d += __shfl_down(d, off);
  }
  if (lane == 0) { als[n] = s; ald[n] = d; }
}

__global__ void k_soft2(const float* __restrict__ als2, const float* __restrict__ ald2,
                        const int* __restrict__ src_s, const int* __restrict__ offs,
                        const int* __restrict__ deg, float* __restrict__ alpha2) {
  int n = blockIdx.x * 256 + threadIdx.x;
  if (n >= N_NODES) return;
  int o = offs[n], dg = deg[n];
  float aldn = ald2[n];
  float m = -1e30f;
  for (int j = 0; j < dg; ++j) {
    float v = als2[src_s[o + j]] + aldn;
    v = (v > 0.f) ? v : NEG_SLOPE * v;
    m = fmaxf(m, v);
  }
  float s = 0.f;
  for (int j = 0; j < dg; ++j) {
    float v = als2[src_s[o + j]] + aldn;
    v = (v > 0.f) ? v : NEG_SLOPE * v;
    s += __expf(v - m);
  }
  float inv = 1.f / s;
  for (int j = 0; j < dg; ++j) {
    float v = als2[src_s[o + j]] + aldn;
    v = (v > 0.f) ? v : NEG_SLOPE * v;
    alpha2[o + j] = __expf(v - m) * inv;
  }
}

__global__ __launch_bounds__(128) void k_agg2(const float* __restrict__ h2,
                                              const float* __restrict__ alpha2,
                                              const int* __restrict__ src_s,
                                              const int* __restrict__ offs,
                                              const int* __restrict__ deg,
                                              const float* __restrict__ b2,
                                              float* __restrict__ out2) {
  int n = blockIdx.x, tid = threadIdx.x;
  int o = offs[n], d = deg[n];
  float acc = 0.f;
  for (int j = 0; j < d; ++j) {
    int e = o + j;
    float a = alpha2[e];
    int sb = src_s[e];
    acc = fmaf(a, h2[(size_t)sb * F_OUT + tid], acc);
  }
  out2[(size_t)n * F_OUT + tid] = fmaxf(acc + b2[tid], 0.f);
}

/* ---------------- pool (batch is sorted) + fc ---------------- */

__global__ __launch_bounds__(128) void k_pool(const float* __restrict__ out2,
                                              const int* __restrict__ batch,
                                              unsigned int* __restrict__ g) {
  int b = blockIdx.x;
  int start = b * 256, end = min(start + 256, N_NODES);
  int f = threadIdx.x;
  int n = start;
  while (n < end) {
    int gc = batch[n];
    float mx = 0.f;
    do {
      mx = fmaxf(mx, out2[(size_t)n * F_OUT + f]);
      ++n;
    } while (n < end && batch[n] == gc);
    atomicMax(&g[gc * F_OUT + f], __float_as_uint(mx));
  }
}

__global__ __launch_bounds__(128) void k_fc(const float* __restrict__ g,
                                            const float* __restrict__ fc_w,
                                            const float* __restrict__ fc_b,
                                            float* __restrict__ out) {
  int b = blockIdx.x, c = threadIdx.x;
  const float* gr = g + (size_t)b * F_OUT;
  float acc = 0.f;
  for (int k = 0; k < F_OUT; ++k) acc = fmaf(gr[k], fc_w[k * F_OUT + c], acc);
  float v = acc + fc_b[c];
  out[(size_t)b * F_OUT + c] = fmaxf(v, 0.f);
}

/* ---------------- launch ---------------- */

extern "C" void kernel_launch(void* const* d_in, const int* in_sizes, int n_in,
                              void* d_out, int out_size, void* d_ws, size_t ws_size,
                              hipStream_t stream) {
  const float* x      = (const float*)d_in[0];
  const int*   ei     = (const int*)  d_in[1];
  const int*   batch  = (const int*)  d_in[2];
  const float* W1     = (const float*)d_in[3];
  const float* a_src1 = (const float*)d_in[4];
  const float* a_dst1 = (const float*)d_in[5];
  const float* b1     = (const float*)d_in[6];
  const float* W2     = (const float*)d_in[7];
  const float* a_src2 = (const float*)d_in[8];
  const float* a_dst2 = (const float*)d_in[9];
  const float* b2     = (const float*)d_in[10];
  const float* fc_w   = (const float*)d_in[11];
  const float* fc_b   = (const float*)d_in[12];
  float* out = (float*)d_out;

  float* ws = (float*)d_ws;
  /* footprint ~= 37.9M floats = 152 MB */
  __hip_bfloat16* out1 = (__hip_bfloat16*)ws;   /* 39,000,000 + 1024 pad bf16 */
  float* h2     = ws + 19501000;          /* 6,400,000 */
  float* out2   = ws + 25901000;          /* 6,400,000 */
  float* als1   = ws + 32301000;          /*   500,000 */
  float* ald1   = ws + 32801000;          /*   500,000 */
  float* als2   = ws + 33301000;          /*    50,000 */
  float* ald2   = ws + 33351000;          /*    50,000 */
  float* alpha1 = ws + 33401000;          /* 3,500,000 */
  float* alpha2 = ws + 36901000;          /*   350,000 */
  float* g      = ws + 37251000;          /*    32,768 */
  float* was    = ws + 37284000;          /*       780 */
  float* wad    = ws + 37285000;          /*       780 */
  __hip_bfloat16* W2T = (__hip_bfloat16*)(ws + 37286000);  /* 102,400 bf16 */
  int* ib     = (int*)(ws + 37338000);
  int* deg    = ib;                        /*  50,000 */
  int* offs   = ib + 50000;
  int* cursor = ib + 100000;
  int* src_s  = ib + 150000;               /* 350,000 */
  int* part   = ib + 500000;               /* 196 */
  int* ppref  = ib + 500224;               /* 196 */

  /* CSR build */
  hipMemsetAsync(deg, 0, N_NODES * sizeof(int), stream);
  k_deg<<<(E_TOT + 255) / 256, 256, 0, stream>>>(ei, deg);
  k_scan1<<<NB, 256, 0, stream>>>(deg, part);
  k_scan2<<<1, 64, 0, stream>>>(part, ppref);
  k_scan3<<<NB, 256, 0, stream>>>(deg, ppref, offs, cursor);
  k_scatter<<<(E_TOT + 255) / 256, 256, 0, stream>>>(ei, cursor, src_s);

  /* weights prep */
  k_prep<<<4, 256, 0, stream>>>(W1, a_src1, a_dst1, was, wad);
  k_w2t<<<(F_OUT * KP + 255) / 256, 256, 0, stream>>>(W2, W2T);
  /* zero out1 tail pad (A k-overrun reads in gemm2m) */
  hipMemsetAsync((char*)out1 + (size_t)N_NODES * D1 * 2, 0, 2048, stream);

  /* layer 1 */
  k_logits1<<<(N_NODES + 31) / 32, 320, 0, stream>>>(x, was, wad, als1, ald1);
  k_soft1<<<(N_NODES * H1 + 255) / 256, 256, 0, stream>>>(als1, ald1, src_s, offs, deg, alpha1);
  k_agg1f<<<N_NODES / 10, 320, 0, stream>>>(x, alpha1, src_s, offs, deg, W1, b1, out1);

  /* layer 2 */
  k_gemm2m<<<(N_NODES + 63) / 64, 256, 0, stream>>>(out1, W2T, h2);
  k_al2<<<N_NODES, 64, 0, stream>>>(h2, a_src2, a_dst2, als2, ald2);
  k_soft2<<<(N_NODES + 255) / 256, 256, 0, stream>>>(als2, ald2, src_s, offs, deg, alpha2);
  k_agg2<<<N_NODES, 128, 0, stream>>>(h2, alpha2, src_s, offs, deg, b2, out2);

  /* pool + fc */
  hipMemsetAsync(g, 0, N_GRAPHS * F_OUT * sizeof(float), stream);
  k_pool<<<NB, 128, 0, stream>>>(out2, batch, (unsigned int*)g);
  k_fc<<<N_GRAPHS, F_OUT, 0, stream>>>(g, fc_w, fc_b, out);
}

// Round 5
// 624.019 us; speedup vs baseline: 1.3121x; 1.0747x over previous
//
#include <hip/hip_runtime.h>
#include <hip/hip_bf16.h>

#define N_NODES 50000
#define N_EDGES 300000
#define E_TOT   350000   /* edges + self loops */
#define N_GRAPHS 256
#define F_IN 78
#define H1 10
#define D1 780           /* H1*F_H1 */
#define F_OUT 128
#define KP 800           /* K padded for MFMA (780 -> 800) */
#define NEG_SLOPE 0.2f
#define NB 196           /* ceil(50000/256) */

typedef float v4f __attribute__((ext_vector_type(4)));
typedef short v8s __attribute__((ext_vector_type(8)));

__device__ __forceinline__ int src_of(int e, const int* __restrict__ ei) {
  return (e < N_EDGES) ? ei[e] : (e - N_EDGES);
}
__device__ __forceinline__ int dst_of(int e, const int* __restrict__ ei) {
  return (e < N_EDGES) ? ei[N_EDGES + e] : (e - N_EDGES);
}

/* ---------------- CSR build: degree, scan, scatter ---------------- */

__global__ void k_deg(const int* __restrict__ ei, int* __restrict__ deg) {
  int e = blockIdx.x * 256 + threadIdx.x;
  if (e >= E_TOT) return;
  atomicAdd(&deg[dst_of(e, ei)], 1);
}

__global__ void k_scan1(const int* __restrict__ deg, int* __restrict__ part) {
  __shared__ int s[256];
  int t = threadIdx.x;
  int i = blockIdx.x * 256 + t;
  s[t] = (i < N_NODES) ? deg[i] : 0;
  __syncthreads();
  for (int d = 128; d > 0; d >>= 1) {
    if (t < d) s[t] += s[t + d];
    __syncthreads();
  }
  if (t == 0) part[blockIdx.x] = s[0];
}

__global__ void k_scan2(const int* __restrict__ part, int* __restrict__ ppref) {
  if (threadIdx.x == 0) {
    int run = 0;
    for (int i = 0; i < NB; ++i) { ppref[i] = run; run += part[i]; }
  }
}

__global__ void k_scan3(const int* __restrict__ deg, const int* __restrict__ ppref,
                        int* __restrict__ offs, int* __restrict__ cursor) {
  __shared__ int s[256];
  int t = threadIdx.x;
  int i = blockIdx.x * 256 + t;
  int v = (i < N_NODES) ? deg[i] : 0;
  s[t] = v;
  __syncthreads();
  for (int d = 1; d < 256; d <<= 1) {
    int u = (t >= d) ? s[t - d] : 0;
    __syncthreads();
    s[t] += u;
    __syncthreads();
  }
  int excl = s[t] - v;
  if (i < N_NODES) {
    int off = ppref[blockIdx.x] + excl;
    offs[i] = off;
    cursor[i] = off;
  }
}

__global__ void k_scatter(const int* __restrict__ ei, int* __restrict__ cursor,
                          int* __restrict__ src_s) {
  int e = blockIdx.x * 256 + threadIdx.x;
  if (e >= E_TOT) return;
  int s = src_of(e, ei);
  int d = dst_of(e, ei);
  int pos = atomicAdd(&cursor[d], 1);
  src_s[pos] = s;
}

/* ---- was[k,h] = sum_f W1[k, h*78+f] * a_src1[h*78+f]; same for wad ---- */

__global__ void k_prep(const float* __restrict__ W1, const float* __restrict__ as1,
                       const float* __restrict__ ad1, float* __restrict__ was,
                       float* __restrict__ wad) {
  int i = blockIdx.x * 256 + threadIdx.x;
  if (i >= F_IN * H1) return;
  int k = i / H1, h = i - k * H1;
  const float* wrow = W1 + (size_t)k * D1 + h * 78;
  const float* ar = as1 + h * 78;
  const float* br = ad1 + h * 78;
  float s = 0.f, d = 0.f;
  for (int f = 0; f < 78; ++f) {
    float w = wrow[f];
    s = fmaf(w, ar[f], s);
    d = fmaf(w, br[f], d);
  }
  was[i] = s;  /* layout [k][h] */
  wad[i] = d;
}

/* ---- als1[n,h] = x[n,:] . was[:,h] ; ald1 likewise (LDS-staged) ---- */

__global__ __launch_bounds__(320) void k_logits1(const float* __restrict__ x,
                                                 const float* __restrict__ was,
                                                 const float* __restrict__ wad,
                                                 float* __restrict__ als,
                                                 float* __restrict__ ald) {
  __shared__ float xs[32][81];
  __shared__ float wl[D1], wl2[D1];
  int tid = threadIdx.x;
  int n0 = blockIdx.x * 32;
  for (int i = tid; i < 32 * F_IN; i += 320) {
    int r = i / F_IN, k = i - r * F_IN;
    int n = n0 + r;
    xs[r][k] = (n < N_NODES) ? x[(size_t)n * F_IN + k] : 0.f;
  }
  for (int i = tid; i < D1; i += 320) { wl[i] = was[i]; wl2[i] = wad[i]; }
  __syncthreads();
  int r = tid / 10, h = tid - r * 10;
  int n = n0 + r;
  float s = 0.f, d = 0.f;
  for (int k = 0; k < F_IN; ++k) {
    float xv = xs[r][k];
    s = fmaf(xv, wl[k * 10 + h], s);
    d = fmaf(xv, wl2[k * 10 + h], d);
  }
  if (n < N_NODES) { als[n * 10 + h] = s; ald[n * 10 + h] = d; }
}

/* ---- fused layer 1: softmax + weighted x gather + per-head matmul with W1
   + bias + ELU -> bf16 out1.   8 nodes/block, 5 waves (wave 4 phase-2 only).
   Softmax is unnormalized-exp (no max-subtract; logits are O(1..8)): per head
   accumulate sum_e w*x and sum_e w, divide at end.  Edge srcs preloaded into
   lanes (one coalesced load), broadcast via shfl+readfirstlane; 4 edges
   unrolled so 4 x-row loads are in flight. ---- */

__global__ __launch_bounds__(320) void k_agg1f(const float* __restrict__ x,
                                               const float* __restrict__ als1,
                                               const float* __restrict__ ald1,
                                               const int* __restrict__ src_s,
                                               const int* __restrict__ offs,
                                               const int* __restrict__ deg,
                                               const float* __restrict__ W1,
                                               const float* __restrict__ b1,
                                               __hip_bfloat16* __restrict__ out1) {
  __shared__ float xagg[8][H1][80];
  int tid = threadIdx.x, wv = tid >> 6, lane = tid & 63;
  int n0 = blockIdx.x * 8;

  if (wv < 4) {
    #pragma unroll
    for (int rep = 0; rep < 2; ++rep) {
      int g = wv * 2 + rep;
      int n = n0 + g;
      int o = offs[n], d = deg[n];
      float aldn[H1], ssum[H1], acc[H1], acc2[H1];
      #pragma unroll
      for (int h = 0; h < H1; ++h) {
        aldn[h] = ald1[n * H1 + h];
        ssum[h] = 0.f; acc[h] = 0.f; acc2[h] = 0.f;
      }
      for (int base = 0; base < d; base += 64) {
        int cnt = min(64, d - base);
        int sb_l = (lane < cnt) ? src_s[o + base + lane] : 0;
        for (int j = 0; j < cnt; j += 4) {
          int sbq[4]; float xaq[4], xbq[4]; bool actq[4];
          #pragma unroll
          for (int q = 0; q < 4; ++q) {
            int jj = j + q;
            actq[q] = jj < cnt;
            int sb = __builtin_amdgcn_readfirstlane(__shfl(sb_l, jj & 63));
            sbq[q] = sb;
            const float* xr = x + (size_t)sb * F_IN;
            float xv = xr[lane];
            float xv2 = (lane < F_IN - 64) ? xr[64 + lane] : 0.f;
            xaq[q] = actq[q] ? xv : 0.f;
            xbq[q] = actq[q] ? xv2 : 0.f;
          }
          #pragma unroll
          for (int q = 0; q < 4; ++q) {
            const float* alr = als1 + (size_t)sbq[q] * H1;
            #pragma unroll
            for (int h = 0; h < H1; ++h) {
              float v = alr[h] + aldn[h];
              v = (v > 0.f) ? v : NEG_SLOPE * v;
              float w = __expf(v);
              w = actq[q] ? w : 0.f;
              ssum[h] += w;
              acc[h] = fmaf(w, xaq[q], acc[h]);
              acc2[h] = fmaf(w, xbq[q], acc2[h]);
            }
          }
        }
      }
      #pragma unroll
      for (int h = 0; h < H1; ++h) {
        float inv = 1.f / ssum[h];
        xagg[g][h][lane] = acc[h] * inv;
        if (lane < 16) xagg[g][h][64 + lane] = (lane < F_IN - 64) ? acc2[h] * inv : 0.f;
      }
    }
  }
  __syncthreads();

  /* phase 2: out1[g, h*78 + j0 + {0,26,52}] = xagg[g,h,:] . W1 cols, +b1, ELU */
  if (tid < 260) {
    int h = tid / 26, j0 = tid - h * 26;
    int c0 = h * 78 + j0;
    float s2[8][3];
    #pragma unroll
    for (int g = 0; g < 8; ++g)
      #pragma unroll
      for (int q = 0; q < 3; ++q) s2[g][q] = 0.f;

    for (int k = 0; k < 76; k += 4) {
      float wq[3][4];
      #pragma unroll
      for (int q = 0; q < 3; ++q)
        #pragma unroll
        for (int kk = 0; kk < 4; ++kk)
          wq[q][kk] = W1[(size_t)(k + kk) * D1 + c0 + q * 26];
      #pragma unroll
      for (int g = 0; g < 8; ++g) {
        float4 xa = *reinterpret_cast<const float4*>(&xagg[g][h][k]);
        #pragma unroll
        for (int q = 0; q < 3; ++q) {
          s2[g][q] = fmaf(xa.x, wq[q][0], s2[g][q]);
          s2[g][q] = fmaf(xa.y, wq[q][1], s2[g][q]);
          s2[g][q] = fmaf(xa.z, wq[q][2], s2[g][q]);
          s2[g][q] = fmaf(xa.w, wq[q][3], s2[g][q]);
        }
      }
    }
    #pragma unroll
    for (int kk = 0; kk < 2; ++kk) {   /* tail k = 76,77 */
      int k = 76 + kk;
      float w0 = W1[(size_t)k * D1 + c0];
      float w1 = W1[(size_t)k * D1 + c0 + 26];
      float w2 = W1[(size_t)k * D1 + c0 + 52];
      #pragma unroll
      for (int g = 0; g < 8; ++g) {
        float xv = xagg[g][h][k];
        s2[g][0] = fmaf(xv, w0, s2[g][0]);
        s2[g][1] = fmaf(xv, w1, s2[g][1]);
        s2[g][2] = fmaf(xv, w2, s2[g][2]);
      }
    }
    #pragma unroll
    for (int q = 0; q < 3; ++q) {
      int c = c0 + q * 26;
      float bv = b1[c];
      #pragma unroll
      for (int g = 0; g < 8; ++g) {
        float v = s2[g][q] + bv;
        v = (v > 0.f) ? v : expm1f(v);  /* ELU */
        out1[(size_t)(n0 + g) * D1 + c] = __float2bfloat16(v);
      }
    }
  }
}

/* ---- W2 [780][128] fp32 -> W2T [128][800] bf16 (zero-padded K) ---- */

__global__ void k_w2t(const float* __restrict__ W2, __hip_bfloat16* __restrict__ Bt) {
  int i = blockIdx.x * 256 + threadIdx.x;
  if (i >= F_OUT * KP) return;
  int c = i / KP, k = i - c * KP;
  float v = (k < D1) ? W2[(size_t)k * F_OUT + c] : 0.f;
  Bt[i] = __float2bfloat16(v);
}

/* ---- GEMM2 via MFMA: h2[50000,128] = out1(bf16) @ W2T^T.
   Block 256 = 4 waves (2x2), tile 64x128, K=800, no LDS. ---- */

__global__ __launch_bounds__(256) void k_gemm2m(const __hip_bfloat16* __restrict__ A,
                                                const __hip_bfloat16* __restrict__ Bt,
                                                float* __restrict__ C) {
  int tid = threadIdx.x;
  int wid = tid >> 6, lane = tid & 63;
  int wr = wid >> 1, wc = wid & 1;
  int m0 = blockIdx.x * 64;
  int row16 = lane & 15, kchunk = (lane >> 4) * 8;
  v4f acc[2][4];
  #pragma unroll
  for (int ri = 0; ri < 2; ++ri)
    #pragma unroll
    for (int nf = 0; nf < 4; ++nf) acc[ri][nf] = (v4f){0.f, 0.f, 0.f, 0.f};

  const unsigned short* Ap = (const unsigned short*)A;
  const unsigned short* Bp = (const unsigned short*)Bt;

  for (int k0 = 0; k0 < KP; k0 += 32) {
    int ka = k0 + kchunk;
    v8s a[2], b[4];
    #pragma unroll
    for (int ri = 0; ri < 2; ++ri) {
      const unsigned short* p = Ap + (size_t)(m0 + wr * 32 + ri * 16 + row16) * D1 + ka;
      union { uint2 q[2]; v8s v; } u;
      u.q[0] = *reinterpret_cast<const uint2*>(p);
      u.q[1] = *reinterpret_cast<const uint2*>(p + 4);
      a[ri] = u.v;
    }
    #pragma unroll
    for (int nf = 0; nf < 4; ++nf) {
      const unsigned short* p = Bp + (size_t)(wc * 64 + nf * 16 + row16) * KP + ka;
      b[nf] = *reinterpret_cast<const v8s*>(p);
    }
    #pragma unroll
    for (int ri = 0; ri < 2; ++ri)
      #pragma unroll
      for (int nf = 0; nf < 4; ++nf)
        acc[ri][nf] = __builtin_amdgcn_mfma_f32_16x16x32_bf16(a[ri], b[nf], acc[ri][nf], 0, 0, 0);
  }
  #pragma unroll
  for (int ri = 0; ri < 2; ++ri) {
    int rbase = m0 + wr * 32 + ri * 16 + (lane >> 4) * 4;
    #pragma unroll
    for (int r = 0; r < 4; ++r) {
      int gm = rbase + r;
      if (gm < N_NODES) {
        #pragma unroll
        for (int nf = 0; nf < 4; ++nf)
          C[(size_t)gm * F_OUT + wc * 64 + nf * 16 + (lane & 15)] = acc[ri][nf][r];
      }
    }
  }
}

/* ---------------- layer 2 attention logits ---------------- */

__global__ __launch_bounds__(64) void k_al2(const float* __restrict__ h2,
                                            const float* __restrict__ asrc,
                                            const float* __restrict__ adst,
                                            float* __restrict__ als,
                                            float* __restrict__ ald) {
  int n = blockIdx.x, lane = threadIdx.x;
  const float* hp = h2 + (size_t)n * F_OUT;
  float h0 = hp[lane], h64 = hp[64 + lane];
  float s = h0 * asrc[lane] + h64 * asrc[64 + lane];
  float d = h0 * adst[lane] + h64 * adst[64 + lane];
  #pragma unroll
  for (int off = 32; off > 0; off >>= 1) {
    s += __shfl_down(s, off);
    d += __shfl_down(d, off);
  }
  if (lane == 0) { als[n] = s; ald[n] = d; }
}

/* ---- fused layer 2: softmax (unnormalized exp) + gather-agg + bias + ReLU.
   4 edges unrolled -> 4 independent src->h2-row chains in flight. ---- */

__global__ __launch_bounds__(128) void k_agg2f(const float* __restrict__ h2,
                                               const float* __restrict__ als2,
                                               const float* __restrict__ ald2,
                                               const int* __restrict__ src_s,
                                               const int* __restrict__ offs,
                                               const int* __restrict__ deg,
                                               const float* __restrict__ b2,
                                               float* __restrict__ out2) {
  int n = blockIdx.x, tid = threadIdx.x;
  int o = offs[n], d = deg[n];
  float aldn = ald2[n];
  float acc = 0.f, ssum = 0.f;
  for (int j = 0; j < d; j += 4) {
    int sq[4]; bool actq[4];
    #pragma unroll
    for (int q = 0; q < 4; ++q) {
      int jj = j + q;
      actq[q] = jj < d;
      sq[q] = src_s[o + min(jj, d - 1)];
    }
    float hq[4];
    #pragma unroll
    for (int q = 0; q < 4; ++q) hq[q] = h2[(size_t)sq[q] * F_OUT + tid];
    #pragma unroll
    for (int q = 0; q < 4; ++q) {
      float v = als2[sq[q]] + aldn;
      v = (v > 0.f) ? v : NEG_SLOPE * v;
      float w = __expf(v);
      w = actq[q] ? w : 0.f;
      ssum += w;
      acc = fmaf(w, hq[q], acc);
    }
  }
  float v = acc / ssum + b2[tid];
  out2[(size_t)n * F_OUT + tid] = fmaxf(v, 0.f);
}

/* ---------------- pool (batch is sorted) + fc ---------------- */

__global__ __launch_bounds__(128) void k_pool(const float* __restrict__ out2,
                                              const int* __restrict__ batch,
                                              unsigned int* __restrict__ g) {
  int b = blockIdx.x;
  int start = b * 256, end = min(start + 256, N_NODES);
  int f = threadIdx.x;
  int n = start;
  while (n < end) {
    int gc = batch[n];
    float mx = 0.f;
    do {
      mx = fmaxf(mx, out2[(size_t)n * F_OUT + f]);
      ++n;
    } while (n < end && batch[n] == gc);
    atomicMax(&g[gc * F_OUT + f], __float_as_uint(mx));
  }
}

__global__ __launch_bounds__(128) void k_fc(const float* __restrict__ g,
                                            const float* __restrict__ fc_w,
                                            const float* __restrict__ fc_b,
                                            float* __restrict__ out) {
  int b = blockIdx.x, c = threadIdx.x;
  const float* gr = g + (size_t)b * F_OUT;
  float acc = 0.f;
  for (int k = 0; k < F_OUT; ++k) acc = fmaf(gr[k], fc_w[k * F_OUT + c], acc);
  float v = acc + fc_b[c];
  out[(size_t)b * F_OUT + c] = fmaxf(v, 0.f);
}

/* ---------------- launch ---------------- */

extern "C" void kernel_launch(void* const* d_in, const int* in_sizes, int n_in,
                              void* d_out, int out_size, void* d_ws, size_t ws_size,
                              hipStream_t stream) {
  const float* x      = (const float*)d_in[0];
  const int*   ei     = (const int*)  d_in[1];
  const int*   batch  = (const int*)  d_in[2];
  const float* W1     = (const float*)d_in[3];
  const float* a_src1 = (const float*)d_in[4];
  const float* a_dst1 = (const float*)d_in[5];
  const float* b1     = (const float*)d_in[6];
  const float* W2     = (const float*)d_in[7];
  const float* a_src2 = (const float*)d_in[8];
  const float* a_dst2 = (const float*)d_in[9];
  const float* b2     = (const float*)d_in[10];
  const float* fc_w   = (const float*)d_in[11];
  const float* fc_b   = (const float*)d_in[12];
  float* out = (float*)d_out;

  float* ws = (float*)d_ws;
  /* footprint ~= 34.0M floats = 136 MB */
  __hip_bfloat16* out1 = (__hip_bfloat16*)ws;   /* 39,000,000 + 2000 pad bf16 */
  float* h2   = ws + 19501000;            /* 6,400,000 */
  float* out2 = ws + 25901000;            /* 6,400,000 */
  float* als1 = ws + 32301000;            /*   500,000 */
  float* ald1 = ws + 32801000;            /*   500,000 */
  float* als2 = ws + 33301000;            /*    50,000 */
  float* ald2 = ws + 33351000;            /*    50,000 */
  float* g    = ws + 33401000;            /*    32,768 */
  float* was  = ws + 33434000;            /*       780 */
  float* wad  = ws + 33435000;            /*       780 */
  __hip_bfloat16* W2T = (__hip_bfloat16*)(ws + 33436000);  /* 102,400 bf16 */
  int* ib     = (int*)(ws + 33488000);
  int* deg    = ib;                        /*  50,000 */
  int* offs   = ib + 50000;
  int* cursor = ib + 100000;
  int* src_s  = ib + 150000;               /* 350,000 */
  int* part   = ib + 500000;               /* 196 */
  int* ppref  = ib + 500224;               /* 196 */

  /* CSR build */
  hipMemsetAsync(deg, 0, N_NODES * sizeof(int), stream);
  k_deg<<<(E_TOT + 255) / 256, 256, 0, stream>>>(ei, deg);
  k_scan1<<<NB, 256, 0, stream>>>(deg, part);
  k_scan2<<<1, 64, 0, stream>>>(part, ppref);
  k_scan3<<<NB, 256, 0, stream>>>(deg, ppref, offs, cursor);
  k_scatter<<<(E_TOT + 255) / 256, 256, 0, stream>>>(ei, cursor, src_s);

  /* weights prep */
  k_prep<<<4, 256, 0, stream>>>(W1, a_src1, a_dst1, was, wad);
  k_w2t<<<(F_OUT * KP + 255) / 256, 256, 0, stream>>>(W2, W2T);
  /* zero out1 tail pad (A k-overrun reads in gemm2m) */
  hipMemsetAsync((char*)out1 + (size_t)N_NODES * D1 * 2, 0, 2048, stream);

  /* layer 1 */
  k_logits1<<<(N_NODES + 31) / 32, 320, 0, stream>>>(x, was, wad, als1, ald1);
  k_agg1f<<<N_NODES / 8, 320, 0, stream>>>(x, als1, ald1, src_s, offs, deg, W1, b1, out1);

  /* layer 2 */
  k_gemm2m<<<(N_NODES + 63) / 64, 256, 0, stream>>>(out1, W2T, h2);
  k_al2<<<N_NODES, 64, 0, stream>>>(h2, a_src2, a_dst2, als2, ald2);
  k_agg2f<<<N_NODES, 128, 0, stream>>>(h2, als2, ald2, src_s, offs, deg, b2, out2);

  /* pool + fc */
  hipMemsetAsync(g, 0, N_GRAPHS * F_OUT * sizeof(float), stream);
  k_pool<<<NB, 128, 0, stream>>>(out2, batch, (unsigned int*)g);
  k_fc<<<N_GRAPHS, F_OUT, 0, stream>>>(g, fc_w, fc_b, out);
}

// Round 6
// 395.017 us; speedup vs baseline: 2.0728x; 1.5797x over previous
//
#include <hip/hip_runtime.h>
#include <hip/hip_bf16.h>

#define N_NODES 50000
#define N_EDGES 300000
#define E_TOT   350000   /* edges + self loops */
#define N_GRAPHS 256
#define F_IN 78
#define H1 10
#define D1 780           /* H1*F_H1 */
#define F_OUT 128
#define KP 800           /* K padded for MFMA gemm2 (780 -> 800) */
#define K1P 96           /* K padded for MFMA agg1 phase2 (78 -> 96) */
#define NEG_SLOPE 0.2f
#define NB 196           /* ceil(50000/256) */

typedef float v4f __attribute__((ext_vector_type(4)));
typedef short v8s __attribute__((ext_vector_type(8)));

__device__ __forceinline__ int src_of(int e, const int* __restrict__ ei) {
  return (e < N_EDGES) ? ei[e] : (e - N_EDGES);
}
__device__ __forceinline__ int dst_of(int e, const int* __restrict__ ei) {
  return (e < N_EDGES) ? ei[N_EDGES + e] : (e - N_EDGES);
}

/* ---------------- CSR build: degree, scan, scatter ---------------- */

__global__ void k_deg(const int* __restrict__ ei, int* __restrict__ deg) {
  int e = blockIdx.x * 256 + threadIdx.x;
  if (e >= E_TOT) return;
  atomicAdd(&deg[dst_of(e, ei)], 1);
}

__global__ void k_scan1(const int* __restrict__ deg, int* __restrict__ part) {
  __shared__ int s[256];
  int t = threadIdx.x;
  int i = blockIdx.x * 256 + t;
  s[t] = (i < N_NODES) ? deg[i] : 0;
  __syncthreads();
  for (int d = 128; d > 0; d >>= 1) {
    if (t < d) s[t] += s[t + d];
    __syncthreads();
  }
  if (t == 0) part[blockIdx.x] = s[0];
}

__global__ void k_scan2(const int* __restrict__ part, int* __restrict__ ppref) {
  if (threadIdx.x == 0) {
    int run = 0;
    for (int i = 0; i < NB; ++i) { ppref[i] = run; run += part[i]; }
  }
}

__global__ void k_scan3(const int* __restrict__ deg, const int* __restrict__ ppref,
                        int* __restrict__ offs, int* __restrict__ cursor) {
  __shared__ int s[256];
  int t = threadIdx.x;
  int i = blockIdx.x * 256 + t;
  int v = (i < N_NODES) ? deg[i] : 0;
  s[t] = v;
  __syncthreads();
  for (int d = 1; d < 256; d <<= 1) {
    int u = (t >= d) ? s[t - d] : 0;
    __syncthreads();
    s[t] += u;
    __syncthreads();
  }
  int excl = s[t] - v;
  if (i < N_NODES) {
    int off = ppref[blockIdx.x] + excl;
    offs[i] = off;
    cursor[i] = off;
  }
}

__global__ void k_scatter(const int* __restrict__ ei, int* __restrict__ cursor,
                          int* __restrict__ src_s, int* __restrict__ dst_s) {
  int e = blockIdx.x * 256 + threadIdx.x;
  if (e >= E_TOT) return;
  int s = src_of(e, ei);
  int d = dst_of(e, ei);
  int pos = atomicAdd(&cursor[d], 1);
  src_s[pos] = s;
  dst_s[pos] = d;
}

/* ---- was[k,h] = sum_f W1[k, h*78+f] * a_src1[h*78+f]; same for wad ---- */

__global__ void k_prep(const float* __restrict__ W1, const float* __restrict__ as1,
                       const float* __restrict__ ad1, float* __restrict__ was,
                       float* __restrict__ wad) {
  int i = blockIdx.x * 256 + threadIdx.x;
  if (i >= F_IN * H1) return;
  int k = i / H1, h = i - k * H1;
  const float* wrow = W1 + (size_t)k * D1 + h * 78;
  const float* ar = as1 + h * 78;
  const float* br = ad1 + h * 78;
  float s = 0.f, d = 0.f;
  for (int f = 0; f < 78; ++f) {
    float w = wrow[f];
    s = fmaf(w, ar[f], s);
    d = fmaf(w, br[f], d);
  }
  was[i] = s;  /* layout [k][h] */
  wad[i] = d;
}

/* ---- als1[n,h] = x[n,:] . was[:,h] ; ald1 likewise (LDS-staged) ---- */

__global__ __launch_bounds__(320) void k_logits1(const float* __restrict__ x,
                                                 const float* __restrict__ was,
                                                 const float* __restrict__ wad,
                                                 float* __restrict__ als,
                                                 float* __restrict__ ald) {
  __shared__ float xs[32][81];
  __shared__ float wl[D1], wl2[D1];
  int tid = threadIdx.x;
  int n0 = blockIdx.x * 32;
  for (int i = tid; i < 32 * F_IN; i += 320) {
    int r = i / F_IN, k = i - r * F_IN;
    int n = n0 + r;
    xs[r][k] = (n < N_NODES) ? x[(size_t)n * F_IN + k] : 0.f;
  }
  for (int i = tid; i < D1; i += 320) { wl[i] = was[i]; wl2[i] = wad[i]; }
  __syncthreads();
  int r = tid / 10, h = tid - r * 10;
  int n = n0 + r;
  float s = 0.f, d = 0.f;
  for (int k = 0; k < F_IN; ++k) {
    float xv = xs[r][k];
    s = fmaf(xv, wl[k * 10 + h], s);
    d = fmaf(xv, wl2[k * 10 + h], d);
  }
  if (n < N_NODES) { als[n * 10 + h] = s; ald[n * 10 + h] = d; }
}

/* ---- edge-parallel raw weights, layer 1: w1[pos,h] = exp(leaky(...)) ---- */

__global__ void k_w1e(const float* __restrict__ als1, const float* __restrict__ ald1,
                      const int* __restrict__ src_s, const int* __restrict__ dst_s,
                      float* __restrict__ w1) {
  int i = blockIdx.x * 256 + threadIdx.x;
  if (i >= E_TOT * H1) return;
  int pos = i / H1, h = i - pos * H1;
  float v = als1[src_s[pos] * H1 + h] + ald1[dst_s[pos] * H1 + h];
  v = (v > 0.f) ? v : NEG_SLOPE * v;
  w1[i] = __expf(v);
}

/* ---- W1 [78][780] fp32 -> W1T [800][96] bf16: W1T[c][k] = W1[k][c] ---- */

__global__ void k_w1t(const float* __restrict__ W1, __hip_bfloat16* __restrict__ T) {
  int i = blockIdx.x * 256 + threadIdx.x;
  if (i >= 800 * K1P) return;
  int r = i / K1P, k = i - r * K1P;
  float v = (r < D1 && k < F_IN) ? W1[(size_t)k * D1 + r] : 0.f;
  T[i] = __float2bfloat16(v);
}

/* ---- fused layer 1: weighted x gather (raw w, fold ssum) -> LDS bf16
   -> per-head MFMA with W1T + bias + ELU -> bf16 out1.
   16 nodes/block, 512 threads = 8 waves; wave w owns nodes 2w, 2w+1. ---- */

__global__ __launch_bounds__(512) void k_agg1f(const float* __restrict__ x,
                                               const float* __restrict__ w1,
                                               const int* __restrict__ src_s,
                                               const int* __restrict__ offs,
                                               const int* __restrict__ deg,
                                               const __hip_bfloat16* __restrict__ W1T,
                                               const float* __restrict__ b1,
                                               __hip_bfloat16* __restrict__ out1) {
  __shared__ __hip_bfloat16 xb[H1][16][104];   /* 33,280 B; rows 16B-aligned */
  int tid = threadIdx.x, wid = tid >> 6, lane = tid & 63;
  int n0 = blockIdx.x * 16;

  /* zero-init LDS (covers k-padding 78..103 and unwritten lanes) */
  {
    unsigned int* p = (unsigned int*)xb;
    for (int i = tid; i < H1 * 16 * 52; i += 512) p[i] = 0u;
  }
  __syncthreads();

  /* phase 1: per-wave weighted gather of x rows, fp32 accum in registers */
  #pragma unroll
  for (int rep = 0; rep < 2; ++rep) {
    int g = wid * 2 + rep;
    int n = n0 + g;
    int o = __builtin_amdgcn_readfirstlane(offs[n]);
    int d = __builtin_amdgcn_readfirstlane(deg[n]);
    float ssum[H1], acc[H1], acc2[H1];
    #pragma unroll
    for (int h = 0; h < H1; ++h) { ssum[h] = 0.f; acc[h] = 0.f; acc2[h] = 0.f; }

    int j = 0;
    for (; j + 2 <= d; j += 2) {
      int e0 = o + j, e1 = o + j + 1;
      int s0 = src_s[e0], s1 = src_s[e1];
      const float* x0 = x + (size_t)s0 * F_IN;
      const float* x1 = x + (size_t)s1 * F_IN;
      float xa0 = x0[lane];
      float xa1 = x1[lane];
      float xb0 = (lane < 14) ? x0[64 + lane] : 0.f;
      float xb1 = (lane < 14) ? x1[64 + lane] : 0.f;
      const float* wp0 = w1 + (size_t)e0 * H1;
      const float* wp1 = w1 + (size_t)e1 * H1;
      #pragma unroll
      for (int h = 0; h < H1; ++h) {
        float wa = wp0[h], wb = wp1[h];
        ssum[h] += wa + wb;
        acc[h] = fmaf(wa, xa0, acc[h]);
        acc[h] = fmaf(wb, xa1, acc[h]);
        acc2[h] = fmaf(wa, xb0, acc2[h]);
        acc2[h] = fmaf(wb, xb1, acc2[h]);
      }
    }
    if (j < d) {
      int e0 = o + j;
      int s0 = src_s[e0];
      const float* x0 = x + (size_t)s0 * F_IN;
      float xa0 = x0[lane];
      float xb0 = (lane < 14) ? x0[64 + lane] : 0.f;
      const float* wp0 = w1 + (size_t)e0 * H1;
      #pragma unroll
      for (int h = 0; h < H1; ++h) {
        float wa = wp0[h];
        ssum[h] += wa;
        acc[h] = fmaf(wa, xa0, acc[h]);
        acc2[h] = fmaf(wa, xb0, acc2[h]);
      }
    }
    #pragma unroll
    for (int h = 0; h < H1; ++h) {
      float inv = 1.f / ssum[h];
      xb[h][g][lane] = __float2bfloat16(acc[h] * inv);
      if (lane < 14) xb[h][g][64 + lane] = __float2bfloat16(acc2[h] * inv);
    }
  }
  __syncthreads();

  /* phase 2: 50 units (h, ntile) over 8 waves; 3 MFMAs each.
     A: xagg[h][node=l&15][k], B: W1T[row=h*78+nt*16+(l&15)][k].  */
  const unsigned short* Bp = (const unsigned short*)W1T;
  int col16 = lane & 15, kq = (lane >> 4) * 8;
  for (int u = wid; u < 50; u += 8) {
    int h = u / 5, nt = u - (u / 5) * 5;
    v4f acc = (v4f){0.f, 0.f, 0.f, 0.f};
    #pragma unroll
    for (int kt = 0; kt < 3; ++kt) {
      v8s a = *reinterpret_cast<const v8s*>(&xb[h][col16][kt * 32 + kq]);
      v8s b = *reinterpret_cast<const v8s*>(
          &Bp[(size_t)(h * 78 + nt * 16 + col16) * K1P + kt * 32 + kq]);
      acc = __builtin_amdgcn_mfma_f32_16x16x32_bf16(a, b, acc, 0, 0, 0);
    }
    int cl = nt * 16 + col16;
    if (cl < 78) {
      int c = h * 78 + cl;
      float bv = b1[c];
      #pragma unroll
      for (int r = 0; r < 4; ++r) {
        int node = (lane >> 4) * 4 + r;
        float v = acc[r] + bv;
        v = (v > 0.f) ? v : expm1f(v);  /* ELU */
        out1[(size_t)(n0 + node) * D1 + c] = __float2bfloat16(v);
      }
    }
  }
}

/* ---- W2 [780][128] fp32 -> W2T [128][800] bf16 (zero-padded K) ---- */

__global__ void k_w2t(const float* __restrict__ W2, __hip_bfloat16* __restrict__ Bt) {
  int i = blockIdx.x * 256 + threadIdx.x;
  if (i >= F_OUT * KP) return;
  int c = i / KP, k = i - c * KP;
  float v = (k < D1) ? W2[(size_t)k * F_OUT + c] : 0.f;
  Bt[i] = __float2bfloat16(v);
}

/* ---- GEMM2 via MFMA: h2[50000,128] = out1(bf16) @ W2T^T.
   Block 256 = 4 waves (2x2), tile 64x128, K=800, no LDS. ---- */

__global__ __launch_bounds__(256) void k_gemm2m(const __hip_bfloat16* __restrict__ A,
                                                const __hip_bfloat16* __restrict__ Bt,
                                                float* __restrict__ C) {
  int tid = threadIdx.x;
  int wid = tid >> 6, lane = tid & 63;
  int wr = wid >> 1, wc = wid & 1;
  int m0 = blockIdx.x * 64;
  int row16 = lane & 15, kchunk = (lane >> 4) * 8;
  v4f acc[2][4];
  #pragma unroll
  for (int ri = 0; ri < 2; ++ri)
    #pragma unroll
    for (int nf = 0; nf < 4; ++nf) acc[ri][nf] = (v4f){0.f, 0.f, 0.f, 0.f};

  const unsigned short* Ap = (const unsigned short*)A;
  const unsigned short* Bp = (const unsigned short*)Bt;

  for (int k0 = 0; k0 < KP; k0 += 32) {
    int ka = k0 + kchunk;
    v8s a[2], b[4];
    #pragma unroll
    for (int ri = 0; ri < 2; ++ri) {
      const unsigned short* p = Ap + (size_t)(m0 + wr * 32 + ri * 16 + row16) * D1 + ka;
      union { uint2 q[2]; v8s v; } u;
      u.q[0] = *reinterpret_cast<const uint2*>(p);
      u.q[1] = *reinterpret_cast<const uint2*>(p + 4);
      a[ri] = u.v;
    }
    #pragma unroll
    for (int nf = 0; nf < 4; ++nf) {
      const unsigned short* p = Bp + (size_t)(wc * 64 + nf * 16 + row16) * KP + ka;
      b[nf] = *reinterpret_cast<const v8s*>(p);
    }
    #pragma unroll
    for (int ri = 0; ri < 2; ++ri)
      #pragma unroll
      for (int nf = 0; nf < 4; ++nf)
        acc[ri][nf] = __builtin_amdgcn_mfma_f32_16x16x32_bf16(a[ri], b[nf], acc[ri][nf], 0, 0, 0);
  }
  #pragma unroll
  for (int ri = 0; ri < 2; ++ri) {
    int rbase = m0 + wr * 32 + ri * 16 + (lane >> 4) * 4;
    #pragma unroll
    for (int r = 0; r < 4; ++r) {
      int gm = rbase + r;
      if (gm < N_NODES) {
        #pragma unroll
        for (int nf = 0; nf < 4; ++nf)
          C[(size_t)gm * F_OUT + wc * 64 + nf * 16 + (lane & 15)] = acc[ri][nf][r];
      }
    }
  }
}

/* ---------------- layer 2 attention logits ---------------- */

__global__ __launch_bounds__(64) void k_al2(const float* __restrict__ h2,
                                            const float* __restrict__ asrc,
                                            const float* __restrict__ adst,
                                            float* __restrict__ als,
                                            float* __restrict__ ald) {
  int n = blockIdx.x, lane = threadIdx.x;
  const float* hp = h2 + (size_t)n * F_OUT;
  float h0 = hp[lane], h64 = hp[64 + lane];
  float s = h0 * asrc[lane] + h64 * asrc[64 + lane];
  float d = h0 * adst[lane] + h64 * adst[64 + lane];
  #pragma unroll
  for (int off = 32; off > 0; off >>= 1) {
    s += __shfl_down(s, off);
    d += __shfl_down(d, off);
  }
  if (lane == 0) { als[n] = s; ald[n] = d; }
}

/* ---- edge-parallel raw weights, layer 2 ---- */

__global__ void k_w2e(const float* __restrict__ als2, const float* __restrict__ ald2,
                      const int* __restrict__ src_s, const int* __restrict__ dst_s,
                      float* __restrict__ w2) {
  int pos = blockIdx.x * 256 + threadIdx.x;
  if (pos >= E_TOT) return;
  float v = als2[src_s[pos]] + ald2[dst_s[pos]];
  v = (v > 0.f) ? v : NEG_SLOPE * v;
  w2[pos] = __expf(v);
}

/* ---- layer 2 aggregation: gather h2 rows with precomputed raw w ---- */

__global__ __launch_bounds__(128) void k_agg2f(const float* __restrict__ h2,
                                               const float* __restrict__ w2,
                                               const int* __restrict__ src_s,
                                               const int* __restrict__ offs,
                                               const int* __restrict__ deg,
                                               const float* __restrict__ b2,
                                               float* __restrict__ out2) {
  int n = blockIdx.x, tid = threadIdx.x;
  int o = __builtin_amdgcn_readfirstlane(offs[n]);
  int d = __builtin_amdgcn_readfirstlane(deg[n]);
  float acc = 0.f, ssum = 0.f;
  int j = 0;
  for (; j + 4 <= d; j += 4) {
    float wq[4], hq[4];
    #pragma unroll
    for (int q = 0; q < 4; ++q) {
      int e = o + j + q;
      wq[q] = w2[e];
      hq[q] = h2[(size_t)src_s[e] * F_OUT + tid];
    }
    #pragma unroll
    for (int q = 0; q < 4; ++q) {
      ssum += wq[q];
      acc = fmaf(wq[q], hq[q], acc);
    }
  }
  for (; j < d; ++j) {
    int e = o + j;
    float w = w2[e];
    ssum += w;
    acc = fmaf(w, h2[(size_t)src_s[e] * F_OUT + tid], acc);
  }
  float v = acc / ssum + b2[tid];
  out2[(size_t)n * F_OUT + tid] = fmaxf(v, 0.f);
}

/* ---------------- pool (batch is sorted) + fc ---------------- */

__global__ __launch_bounds__(128) void k_pool(const float* __restrict__ out2,
                                              const int* __restrict__ batch,
                                              unsigned int* __restrict__ g) {
  int b = blockIdx.x;
  int start = b * 256, end = min(start + 256, N_NODES);
  int f = threadIdx.x;
  int n = start;
  while (n < end) {
    int gc = batch[n];
    float mx = 0.f;
    do {
      mx = fmaxf(mx, out2[(size_t)n * F_OUT + f]);
      ++n;
    } while (n < end && batch[n] == gc);
    atomicMax(&g[gc * F_OUT + f], __float_as_uint(mx));
  }
}

__global__ __launch_bounds__(128) void k_fc(const float* __restrict__ g,
                                            const float* __restrict__ fc_w,
                                            const float* __restrict__ fc_b,
                                            float* __restrict__ out) {
  int b = blockIdx.x, c = threadIdx.x;
  const float* gr = g + (size_t)b * F_OUT;
  float acc = 0.f;
  for (int k = 0; k < F_OUT; ++k) acc = fmaf(gr[k], fc_w[k * F_OUT + c], acc);
  float v = acc + fc_b[c];
  out[(size_t)b * F_OUT + c] = fmaxf(v, 0.f);
}

/* ---------------- launch ---------------- */

extern "C" void kernel_launch(void* const* d_in, const int* in_sizes, int n_in,
                              void* d_out, int out_size, void* d_ws, size_t ws_size,
                              hipStream_t stream) {
  const float* x      = (const float*)d_in[0];
  const int*   ei     = (const int*)  d_in[1];
  const int*   batch  = (const int*)  d_in[2];
  const float* W1     = (const float*)d_in[3];
  const float* a_src1 = (const float*)d_in[4];
  const float* a_dst1 = (const float*)d_in[5];
  const float* b1     = (const float*)d_in[6];
  const float* W2     = (const float*)d_in[7];
  const float* a_src2 = (const float*)d_in[8];
  const float* a_dst2 = (const float*)d_in[9];
  const float* b2     = (const float*)d_in[10];
  const float* fc_w   = (const float*)d_in[11];
  const float* fc_b   = (const float*)d_in[12];
  float* out = (float*)d_out;

  float* ws = (float*)d_ws;
  /* footprint ~= 38.2M floats = 153 MB */
  __hip_bfloat16* out1 = (__hip_bfloat16*)ws;   /* 39,000,000 + pad bf16 */
  float* h2   = ws + 19501000;            /* 6,400,000 */
  float* out2 = ws + 25901000;            /* 6,400,000 */
  float* als1 = ws + 32301000;            /*   500,000 */
  float* ald1 = ws + 32801000;            /*   500,000 */
  float* als2 = ws + 33301000;            /*    50,000 */
  float* ald2 = ws + 33351000;            /*    50,000 */
  float* g    = ws + 33401000;            /*    32,768 */
  float* was  = ws + 33434000;            /*       780 */
  float* wad  = ws + 33435000;            /*       780 */
  __hip_bfloat16* W2T = (__hip_bfloat16*)(ws + 33436000);  /* 102,400 bf16 */
  __hip_bfloat16* W1T = (__hip_bfloat16*)(ws + 33488000);  /*  76,800 bf16 */
  float* w1   = ws + 33527000;            /* 3,500,000 */
  float* w2   = ws + 37027000;            /*   350,000 */
  int* ib     = (int*)(ws + 37377000);
  int* deg    = ib;                        /*  50,000 */
  int* offs   = ib + 50000;
  int* cursor = ib + 100000;
  int* src_s  = ib + 150000;               /* 350,000 */
  int* dst_s  = ib + 500000;               /* 350,000 */
  int* part   = ib + 850000;               /* 196 */
  int* ppref  = ib + 850224;               /* 196 */

  /* CSR build */
  hipMemsetAsync(deg, 0, N_NODES * sizeof(int), stream);
  k_deg<<<(E_TOT + 255) / 256, 256, 0, stream>>>(ei, deg);
  k_scan1<<<NB, 256, 0, stream>>>(deg, part);
  k_scan2<<<1, 64, 0, stream>>>(part, ppref);
  k_scan3<<<NB, 256, 0, stream>>>(deg, ppref, offs, cursor);
  k_scatter<<<(E_TOT + 255) / 256, 256, 0, stream>>>(ei, cursor, src_s, dst_s);

  /* weights prep */
  k_prep<<<4, 256, 0, stream>>>(W1, a_src1, a_dst1, was, wad);
  k_w1t<<<(800 * K1P + 255) / 256, 256, 0, stream>>>(W1, W1T);
  k_w2t<<<(F_OUT * KP + 255) / 256, 256, 0, stream>>>(W2, W2T);
  /* zero out1 tail pad (A k-overrun reads in gemm2m) */
  hipMemsetAsync((char*)out1 + (size_t)N_NODES * D1 * 2, 0, 2048, stream);

  /* layer 1 */
  k_logits1<<<(N_NODES + 31) / 32, 320, 0, stream>>>(x, was, wad, als1, ald1);
  k_w1e<<<(E_TOT * H1 + 255) / 256, 256, 0, stream>>>(als1, ald1, src_s, dst_s, w1);
  k_agg1f<<<N_NODES / 16, 512, 0, stream>>>(x, w1, src_s, offs, deg, W1T, b1, out1);

  /* layer 2 */
  k_gemm2m<<<(N_NODES + 63) / 64, 256, 0, stream>>>(out1, W2T, h2);
  k_al2<<<N_NODES, 64, 0, stream>>>(h2, a_src2, a_dst2, als2, ald2);
  k_w2e<<<(E_TOT + 255) / 256, 256, 0, stream>>>(als2, ald2, src_s, dst_s, w2);
  k_agg2f<<<N_NODES, 128, 0, stream>>>(h2, w2, src_s, offs, deg, b2, out2);

  /* pool + fc */
  hipMemsetAsync(g, 0, N_GRAPHS * F_OUT * sizeof(float), stream);
  k_pool<<<NB, 128, 0, stream>>>(out2, batch, (unsigned int*)g);
  k_fc<<<N_GRAPHS, F_OUT, 0, stream>>>(g, fc_w, fc_b, out);
}

// Round 7
// 295.452 us; speedup vs baseline: 2.7713x; 1.3370x over previous
//
#include <hip/hip_runtime.h>
#include <hip/hip_bf16.h>

#define N_NODES 50000
#define N_EDGES 300000
#define E_TOT   350000   /* edges + self loops */
#define N_GRAPHS 256
#define F_IN 78
#define H1 10
#define D1 780           /* H1*F_H1 */
#define F_OUT 128
#define KP 800           /* K padded for MFMA gemm2 (780 -> 800) */
#define K1P 96           /* K padded for MFMA agg1 phase2 (78 -> 96) */
#define NEG_SLOPE 0.2f
#define NB 196           /* ceil(50000/256) */

typedef float v4f __attribute__((ext_vector_type(4)));
typedef short v8s __attribute__((ext_vector_type(8)));

__device__ __forceinline__ int src_of(int e, const int* __restrict__ ei) {
  return (e < N_EDGES) ? ei[e] : (e - N_EDGES);
}
__device__ __forceinline__ int dst_of(int e, const int* __restrict__ ei) {
  return (e < N_EDGES) ? ei[N_EDGES + e] : (e - N_EDGES);
}

/* ---------------- CSR build: degree, scan, scatter ---------------- */

__global__ void k_deg(const int* __restrict__ ei, int* __restrict__ deg) {
  int e = blockIdx.x * 256 + threadIdx.x;
  if (e >= E_TOT) return;
  atomicAdd(&deg[dst_of(e, ei)], 1);
}

__global__ void k_scan1(const int* __restrict__ deg, int* __restrict__ part) {
  __shared__ int s[256];
  int t = threadIdx.x;
  int i = blockIdx.x * 256 + t;
  s[t] = (i < N_NODES) ? deg[i] : 0;
  __syncthreads();
  for (int d = 128; d > 0; d >>= 1) {
    if (t < d) s[t] += s[t + d];
    __syncthreads();
  }
  if (t == 0) part[blockIdx.x] = s[0];
}

__global__ void k_scan2(const int* __restrict__ part, int* __restrict__ ppref) {
  if (threadIdx.x == 0) {
    int run = 0;
    for (int i = 0; i < NB; ++i) { ppref[i] = run; run += part[i]; }
  }
}

__global__ void k_scan3(const int* __restrict__ deg, const int* __restrict__ ppref,
                        int* __restrict__ offs, int* __restrict__ cursor) {
  __shared__ int s[256];
  int t = threadIdx.x;
  int i = blockIdx.x * 256 + t;
  int v = (i < N_NODES) ? deg[i] : 0;
  s[t] = v;
  __syncthreads();
  for (int d = 1; d < 256; d <<= 1) {
    int u = (t >= d) ? s[t - d] : 0;
    __syncthreads();
    s[t] += u;
    __syncthreads();
  }
  int excl = s[t] - v;
  if (i < N_NODES) {
    int off = ppref[blockIdx.x] + excl;
    offs[i] = off;
    cursor[i] = off;
  }
}

__global__ void k_scatter(const int* __restrict__ ei, int* __restrict__ cursor,
                          int* __restrict__ src_s, int* __restrict__ dst_s) {
  int e = blockIdx.x * 256 + threadIdx.x;
  if (e >= E_TOT) return;
  int s = src_of(e, ei);
  int d = dst_of(e, ei);
  int pos = atomicAdd(&cursor[d], 1);
  src_s[pos] = s;
  dst_s[pos] = d;
}

/* ---- was[k,h] = sum_f W1[k, h*78+f] * a_src1[h*78+f]; same for wad ---- */

__global__ void k_prep(const float* __restrict__ W1, const float* __restrict__ as1,
                       const float* __restrict__ ad1, float* __restrict__ was,
                       float* __restrict__ wad) {
  int i = blockIdx.x * 256 + threadIdx.x;
  if (i >= F_IN * H1) return;
  int k = i / H1, h = i - k * H1;
  const float* wrow = W1 + (size_t)k * D1 + h * 78;
  const float* ar = as1 + h * 78;
  const float* br = ad1 + h * 78;
  float s = 0.f, d = 0.f;
  for (int f = 0; f < 78; ++f) {
    float w = wrow[f];
    s = fmaf(w, ar[f], s);
    d = fmaf(w, br[f], d);
  }
  was[i] = s;  /* layout [k][h] */
  wad[i] = d;
}

/* ---- als1[n,h] = x[n,:] . was[:,h] ; ald1 likewise (LDS-staged) ---- */

__global__ __launch_bounds__(320) void k_logits1(const float* __restrict__ x,
                                                 const float* __restrict__ was,
                                                 const float* __restrict__ wad,
                                                 float* __restrict__ als,
                                                 float* __restrict__ ald) {
  __shared__ float xs[32][81];
  __shared__ float wl[D1], wl2[D1];
  int tid = threadIdx.x;
  int n0 = blockIdx.x * 32;
  for (int i = tid; i < 32 * F_IN; i += 320) {
    int r = i / F_IN, k = i - r * F_IN;
    int n = n0 + r;
    xs[r][k] = (n < N_NODES) ? x[(size_t)n * F_IN + k] : 0.f;
  }
  for (int i = tid; i < D1; i += 320) { wl[i] = was[i]; wl2[i] = wad[i]; }
  __syncthreads();
  int r = tid / 10, h = tid - r * 10;
  int n = n0 + r;
  float s = 0.f, d = 0.f;
  for (int k = 0; k < F_IN; ++k) {
    float xv = xs[r][k];
    s = fmaf(xv, wl[k * 10 + h], s);
    d = fmaf(xv, wl2[k * 10 + h], d);
  }
  if (n < N_NODES) { als[n * 10 + h] = s; ald[n * 10 + h] = d; }
}

/* ---- edge-parallel raw weights, layer 1: w1[pos,h] = exp(leaky(...)) ---- */

__global__ void k_w1e(const float* __restrict__ als1, const float* __restrict__ ald1,
                      const int* __restrict__ src_s, const int* __restrict__ dst_s,
                      float* __restrict__ w1) {
  int i = blockIdx.x * 256 + threadIdx.x;
  if (i >= E_TOT * H1) return;
  int pos = i / H1, h = i - pos * H1;
  float v = als1[src_s[pos] * H1 + h] + ald1[dst_s[pos] * H1 + h];
  v = (v > 0.f) ? v : NEG_SLOPE * v;
  w1[i] = __expf(v);
}

/* ---- W1 [78][780] fp32 -> W1T [800][96] bf16: W1T[c][k] = W1[k][c] ---- */

__global__ void k_w1t(const float* __restrict__ W1, __hip_bfloat16* __restrict__ T) {
  int i = blockIdx.x * 256 + threadIdx.x;
  if (i >= 800 * K1P) return;
  int r = i / K1P, k = i - r * K1P;
  float v = (r < D1 && k < F_IN) ? W1[(size_t)k * D1 + r] : 0.f;
  T[i] = __float2bfloat16(v);
}

/* ---- fused layer 1: weighted x gather (raw w, fold ssum) -> LDS bf16
   -> per-head MFMA with W1T + bias + ELU -> bf16 out1.
   16 nodes/block, 512 threads = 8 waves; wave w owns nodes 2w, 2w+1. ---- */

__global__ __launch_bounds__(512) void k_agg1f(const float* __restrict__ x,
                                               const float* __restrict__ w1,
                                               const int* __restrict__ src_s,
                                               const int* __restrict__ offs,
                                               const int* __restrict__ deg,
                                               const __hip_bfloat16* __restrict__ W1T,
                                               const float* __restrict__ b1,
                                               __hip_bfloat16* __restrict__ out1) {
  __shared__ __hip_bfloat16 xb[H1][16][104];   /* 33,280 B; rows 16B-aligned */
  int tid = threadIdx.x, wid = tid >> 6, lane = tid & 63;
  int n0 = blockIdx.x * 16;

  /* zero-init LDS (covers k-padding 78..103 and unwritten lanes) */
  {
    unsigned int* p = (unsigned int*)xb;
    for (int i = tid; i < H1 * 16 * 52; i += 512) p[i] = 0u;
  }
  __syncthreads();

  /* phase 1: per-wave weighted gather of x rows, fp32 accum in registers */
  #pragma unroll
  for (int rep = 0; rep < 2; ++rep) {
    int g = wid * 2 + rep;
    int n = n0 + g;
    int o = __builtin_amdgcn_readfirstlane(offs[n]);
    int d = __builtin_amdgcn_readfirstlane(deg[n]);
    float ssum[H1], acc[H1], acc2[H1];
    #pragma unroll
    for (int h = 0; h < H1; ++h) { ssum[h] = 0.f; acc[h] = 0.f; acc2[h] = 0.f; }

    int j = 0;
    for (; j + 2 <= d; j += 2) {
      int e0 = o + j, e1 = o + j + 1;
      int s0 = src_s[e0], s1 = src_s[e1];
      const float* x0 = x + (size_t)s0 * F_IN;
      const float* x1 = x + (size_t)s1 * F_IN;
      float xa0 = x0[lane];
      float xa1 = x1[lane];
      float xb0 = (lane < 14) ? x0[64 + lane] : 0.f;
      float xb1 = (lane < 14) ? x1[64 + lane] : 0.f;
      const float* wp0 = w1 + (size_t)e0 * H1;
      const float* wp1 = w1 + (size_t)e1 * H1;
      #pragma unroll
      for (int h = 0; h < H1; ++h) {
        float wa = wp0[h], wb = wp1[h];
        ssum[h] += wa + wb;
        acc[h] = fmaf(wa, xa0, acc[h]);
        acc[h] = fmaf(wb, xa1, acc[h]);
        acc2[h] = fmaf(wa, xb0, acc2[h]);
        acc2[h] = fmaf(wb, xb1, acc2[h]);
      }
    }
    if (j < d) {
      int e0 = o + j;
      int s0 = src_s[e0];
      const float* x0 = x + (size_t)s0 * F_IN;
      float xa0 = x0[lane];
      float xb0 = (lane < 14) ? x0[64 + lane] : 0.f;
      const float* wp0 = w1 + (size_t)e0 * H1;
      #pragma unroll
      for (int h = 0; h < H1; ++h) {
        float wa = wp0[h];
        ssum[h] += wa;
        acc[h] = fmaf(wa, xa0, acc[h]);
        acc2[h] = fmaf(wa, xb0, acc2[h]);
      }
    }
    #pragma unroll
    for (int h = 0; h < H1; ++h) {
      float inv = 1.f / ssum[h];
      xb[h][g][lane] = __float2bfloat16(acc[h] * inv);
      if (lane < 14) xb[h][g][64 + lane] = __float2bfloat16(acc2[h] * inv);
    }
  }
  __syncthreads();

  /* phase 2: 50 units (h, ntile) over 8 waves; 3 MFMAs each. */
  const unsigned short* Bp = (const unsigned short*)W1T;
  int col16 = lane & 15, kq = (lane >> 4) * 8;
  for (int u = wid; u < 50; u += 8) {
    int h = u / 5, nt = u - (u / 5) * 5;
    v4f acc = (v4f){0.f, 0.f, 0.f, 0.f};
    #pragma unroll
    for (int kt = 0; kt < 3; ++kt) {
      v8s a = *reinterpret_cast<const v8s*>(&xb[h][col16][kt * 32 + kq]);
      v8s b = *reinterpret_cast<const v8s*>(
          &Bp[(size_t)(h * 78 + nt * 16 + col16) * K1P + kt * 32 + kq]);
      acc = __builtin_amdgcn_mfma_f32_16x16x32_bf16(a, b, acc, 0, 0, 0);
    }
    int cl = nt * 16 + col16;
    if (cl < 78) {
      int c = h * 78 + cl;
      float bv = b1[c];
      #pragma unroll
      for (int r = 0; r < 4; ++r) {
        int node = (lane >> 4) * 4 + r;
        float v = acc[r] + bv;
        v = (v > 0.f) ? v : expm1f(v);  /* ELU */
        out1[(size_t)(n0 + node) * D1 + c] = __float2bfloat16(v);
      }
    }
  }
}

/* ---- W2 [780][128] fp32 -> W2T [128][800] bf16 (zero-padded K) ---- */

__global__ void k_w2t(const float* __restrict__ W2, __hip_bfloat16* __restrict__ Bt) {
  int i = blockIdx.x * 256 + threadIdx.x;
  if (i >= F_OUT * KP) return;
  int c = i / KP, k = i - c * KP;
  float v = (k < D1) ? W2[(size_t)k * F_OUT + c] : 0.f;
  Bt[i] = __float2bfloat16(v);
}

/* ---- GEMM2 via MFMA: h2[50000,128] = out1(bf16) @ W2T^T.
   Block 256 = 4 waves (2x2), tile 64x128, K=800, no LDS. ---- */

__global__ __launch_bounds__(256) void k_gemm2m(const __hip_bfloat16* __restrict__ A,
                                                const __hip_bfloat16* __restrict__ Bt,
                                                float* __restrict__ C) {
  int tid = threadIdx.x;
  int wid = tid >> 6, lane = tid & 63;
  int wr = wid >> 1, wc = wid & 1;
  int m0 = blockIdx.x * 64;
  int row16 = lane & 15, kchunk = (lane >> 4) * 8;
  v4f acc[2][4];
  #pragma unroll
  for (int ri = 0; ri < 2; ++ri)
    #pragma unroll
    for (int nf = 0; nf < 4; ++nf) acc[ri][nf] = (v4f){0.f, 0.f, 0.f, 0.f};

  const unsigned short* Ap = (const unsigned short*)A;
  const unsigned short* Bp = (const unsigned short*)Bt;

  for (int k0 = 0; k0 < KP; k0 += 32) {
    int ka = k0 + kchunk;
    v8s a[2], b[4];
    #pragma unroll
    for (int ri = 0; ri < 2; ++ri) {
      const unsigned short* p = Ap + (size_t)(m0 + wr * 32 + ri * 16 + row16) * D1 + ka;
      union { uint2 q[2]; v8s v; } u;
      u.q[0] = *reinterpret_cast<const uint2*>(p);
      u.q[1] = *reinterpret_cast<const uint2*>(p + 4);
      a[ri] = u.v;
    }
    #pragma unroll
    for (int nf = 0; nf < 4; ++nf) {
      const unsigned short* p = Bp + (size_t)(wc * 64 + nf * 16 + row16) * KP + ka;
      b[nf] = *reinterpret_cast<const v8s*>(p);
    }
    #pragma unroll
    for (int ri = 0; ri < 2; ++ri)
      #pragma unroll
      for (int nf = 0; nf < 4; ++nf)
        acc[ri][nf] = __builtin_amdgcn_mfma_f32_16x16x32_bf16(a[ri], b[nf], acc[ri][nf], 0, 0, 0);
  }
  #pragma unroll
  for (int ri = 0; ri < 2; ++ri) {
    int rbase = m0 + wr * 32 + ri * 16 + (lane >> 4) * 4;
    #pragma unroll
    for (int r = 0; r < 4; ++r) {
      int gm = rbase + r;
      if (gm < N_NODES) {
        #pragma unroll
        for (int nf = 0; nf < 4; ++nf)
          C[(size_t)gm * F_OUT + wc * 64 + nf * 16 + (lane & 15)] = acc[ri][nf][r];
      }
    }
  }
}

/* ---------------- layer 2 attention logits ---------------- */

__global__ __launch_bounds__(64) void k_al2(const float* __restrict__ h2,
                                            const float* __restrict__ asrc,
                                            const float* __restrict__ adst,
                                            float* __restrict__ als,
                                            float* __restrict__ ald) {
  int n = blockIdx.x, lane = threadIdx.x;
  const float* hp = h2 + (size_t)n * F_OUT;
  float h0 = hp[lane], h64 = hp[64 + lane];
  float s = h0 * asrc[lane] + h64 * asrc[64 + lane];
  float d = h0 * adst[lane] + h64 * adst[64 + lane];
  #pragma unroll
  for (int off = 32; off > 0; off >>= 1) {
    s += __shfl_down(s, off);
    d += __shfl_down(d, off);
  }
  if (lane == 0) { als[n] = s; ald[n] = d; }
}

/* ---- edge-parallel raw weights, layer 2 ---- */

__global__ void k_w2e(const float* __restrict__ als2, const float* __restrict__ ald2,
                      const int* __restrict__ src_s, const int* __restrict__ dst_s,
                      float* __restrict__ w2) {
  int pos = blockIdx.x * 256 + threadIdx.x;
  if (pos >= E_TOT) return;
  float v = als2[src_s[pos]] + ald2[dst_s[pos]];
  v = (v > 0.f) ? v : NEG_SLOPE * v;
  w2[pos] = __expf(v);
}

/* ---- layer 2 aggregation + bias + ReLU + FUSED graph max-pool.
   g[batch[n]*128+f] accumulated via uint atomicMax (values >= 0). ---- */

__global__ __launch_bounds__(128) void k_agg2f(const float* __restrict__ h2,
                                               const float* __restrict__ w2,
                                               const int* __restrict__ src_s,
                                               const int* __restrict__ offs,
                                               const int* __restrict__ deg,
                                               const float* __restrict__ b2,
                                               const int* __restrict__ batch,
                                               unsigned int* __restrict__ g) {
  int n = blockIdx.x, tid = threadIdx.x;
  int o = __builtin_amdgcn_readfirstlane(offs[n]);
  int d = __builtin_amdgcn_readfirstlane(deg[n]);
  float acc = 0.f, ssum = 0.f;
  int j = 0;
  for (; j + 4 <= d; j += 4) {
    float wq[4], hq[4];
    #pragma unroll
    for (int q = 0; q < 4; ++q) {
      int e = o + j + q;
      wq[q] = w2[e];
      hq[q] = h2[(size_t)src_s[e] * F_OUT + tid];
    }
    #pragma unroll
    for (int q = 0; q < 4; ++q) {
      ssum += wq[q];
      acc = fmaf(wq[q], hq[q], acc);
    }
  }
  for (; j < d; ++j) {
    int e = o + j;
    float w = w2[e];
    ssum += w;
    acc = fmaf(w, h2[(size_t)src_s[e] * F_OUT + tid], acc);
  }
  float v = fmaxf(acc / ssum + b2[tid], 0.f);
  int gc = __builtin_amdgcn_readfirstlane(batch[n]);
  atomicMax(&g[gc * F_OUT + tid], __float_as_uint(v));
}

/* ---------------- fc ---------------- */

__global__ __launch_bounds__(128) void k_fc(const float* __restrict__ g,
                                            const float* __restrict__ fc_w,
                                            const float* __restrict__ fc_b,
                                            float* __restrict__ out) {
  int b = blockIdx.x, c = threadIdx.x;
  const float* gr = g + (size_t)b * F_OUT;
  float acc = 0.f;
  for (int k = 0; k < F_OUT; ++k) acc = fmaf(gr[k], fc_w[k * F_OUT + c], acc);
  float v = acc + fc_b[c];
  out[(size_t)b * F_OUT + c] = fmaxf(v, 0.f);
}

/* ---------------- launch ---------------- */

extern "C" void kernel_launch(void* const* d_in, const int* in_sizes, int n_in,
                              void* d_out, int out_size, void* d_ws, size_t ws_size,
                              hipStream_t stream) {
  const float* x      = (const float*)d_in[0];
  const int*   ei     = (const int*)  d_in[1];
  const int*   batch  = (const int*)  d_in[2];
  const float* W1     = (const float*)d_in[3];
  const float* a_src1 = (const float*)d_in[4];
  const float* a_dst1 = (const float*)d_in[5];
  const float* b1     = (const float*)d_in[6];
  const float* W2     = (const float*)d_in[7];
  const float* a_src2 = (const float*)d_in[8];
  const float* a_dst2 = (const float*)d_in[9];
  const float* b2     = (const float*)d_in[10];
  const float* fc_w   = (const float*)d_in[11];
  const float* fc_b   = (const float*)d_in[12];
  float* out = (float*)d_out;

  float* ws = (float*)d_ws;
  __hip_bfloat16* out1 = (__hip_bfloat16*)ws;   /* 39,000,000 + pad bf16 */
  float* h2   = ws + 19501000;            /* 6,400,000 */
  float* als1 = ws + 25901000;            /*   500,000 */
  float* ald1 = ws + 26401000;            /*   500,000 */
  float* als2 = ws + 26901000;            /*    50,000 */
  float* ald2 = ws + 26951000;            /*    50,000 */
  float* g    = ws + 27001000;            /*    32,768 */
  float* was  = ws + 27034000;            /*       780 */
  float* wad  = ws + 27035000;            /*       780 */
  __hip_bfloat16* W2T = (__hip_bfloat16*)(ws + 27036000);  /* 102,400 bf16 */
  __hip_bfloat16* W1T = (__hip_bfloat16*)(ws + 27088000);  /*  76,800 bf16 */
  float* w1   = ws + 27127000;            /* 3,500,000 */
  float* w2   = ws + 30627000;            /*   350,000 */
  int* ib     = (int*)(ws + 30977000);
  int* deg    = ib;                        /*  50,000 */
  int* offs   = ib + 50000;
  int* cursor = ib + 100000;
  int* src_s  = ib + 150000;               /* 350,000 */
  int* dst_s  = ib + 500000;               /* 350,000 */
  int* part   = ib + 850000;               /* 196 */
  int* ppref  = ib + 850224;               /* 196 */

  /* CSR build */
  hipMemsetAsync(deg, 0, N_NODES * sizeof(int), stream);
  k_deg<<<(E_TOT + 255) / 256, 256, 0, stream>>>(ei, deg);
  k_scan1<<<NB, 256, 0, stream>>>(deg, part);
  k_scan2<<<1, 64, 0, stream>>>(part, ppref);
  k_scan3<<<NB, 256, 0, stream>>>(deg, ppref, offs, cursor);
  k_scatter<<<(E_TOT + 255) / 256, 256, 0, stream>>>(ei, cursor, src_s, dst_s);

  /* weights prep */
  k_prep<<<4, 256, 0, stream>>>(W1, a_src1, a_dst1, was, wad);
  k_w1t<<<(800 * K1P + 255) / 256, 256, 0, stream>>>(W1, W1T);
  k_w2t<<<(F_OUT * KP + 255) / 256, 256, 0, stream>>>(W2, W2T);
  /* zero out1 tail pad (A k-overrun reads in gemm2m) */
  hipMemsetAsync((char*)out1 + (size_t)N_NODES * D1 * 2, 0, 2048, stream);
  /* zero pool accumulator (used by fused agg2f) */
  hipMemsetAsync(g, 0, N_GRAPHS * F_OUT * sizeof(float), stream);

  /* layer 1 */
  k_logits1<<<(N_NODES + 31) / 32, 320, 0, stream>>>(x, was, wad, als1, ald1);
  k_w1e<<<(E_TOT * H1 + 255) / 256, 256, 0, stream>>>(als1, ald1, src_s, dst_s, w1);
  k_agg1f<<<N_NODES / 16, 512, 0, stream>>>(x, w1, src_s, offs, deg, W1T, b1, out1);

  /* layer 2 (pool fused into agg2f) */
  k_gemm2m<<<(N_NODES + 63) / 64, 256, 0, stream>>>(out1, W2T, h2);
  k_al2<<<N_NODES, 64, 0, stream>>>(h2, a_src2, a_dst2, als2, ald2);
  k_w2e<<<(E_TOT + 255) / 256, 256, 0, stream>>>(als2, ald2, src_s, dst_s, w2);
  k_agg2f<<<N_NODES, 128, 0, stream>>>(h2, w2, src_s, offs, deg, b2, batch, (unsigned int*)g);

  /* fc */
  k_fc<<<N_GRAPHS, F_OUT, 0, stream>>>(g, fc_w, fc_b, out);
}